// Round 12
// baseline (1047.467 us; speedup 1.0000x reference)
//
#include <hip/hip_runtime.h>
#include <hip/hip_cooperative_groups.h>
#include <math.h>

namespace cg = cooperative_groups;

#define S_LEN 2048
#define E_DIM 768
#define NH    12
#define HD    64
#define MU    (1.0f/2048.0f)
#define LN_EPS 1e-12f
#define CH2   32            // sinkhorn_all chunk rows
#define NCH2  (S_LEN/CH2)   // 64 chunks

typedef __attribute__((ext_vector_type(8))) short bf16x8;   // 8 bf16 (4 VGPRs)
typedef __attribute__((ext_vector_type(4))) float f32x4;    // MFMA accumulator
typedef __attribute__((ext_vector_type(2))) float f32x2;
typedef long i64_t;                                          // 8 fp8 (2 VGPRs)

__device__ __forceinline__ unsigned short f2bf(float f) {   // RNE fp32->bf16
    unsigned u = __float_as_uint(f);
    u += 0x7fff + ((u >> 16) & 1);
    return (unsigned short)(u >> 16);
}
__device__ __forceinline__ float bf2f(unsigned short h) {
    return __uint_as_float(((unsigned)h) << 16);
}

// ---- fp8 e4m3 (OCP) helpers ----
__device__ __forceinline__ unsigned char fp8_enc(float f) {
#if __has_builtin(__builtin_amdgcn_cvt_pk_fp8_f32)
    return (unsigned char)(__builtin_amdgcn_cvt_pk_fp8_f32(f, f, 0, false) & 0xFF);
#else
    float m = fminf(fabsf(f), 448.f) * 0x1p-120f;
    unsigned b = __float_as_uint(m);
    unsigned s = (__float_as_uint(f) >> 24) & 0x80u;
    b += 0x7FFFFu + ((b >> 20) & 1u);
    return (unsigned char)(s | ((b >> 20) & 0x7Fu));
#endif
}
__device__ __forceinline__ unsigned fp8_pack4(float e0, float e1, float e2, float e3) {
#if __has_builtin(__builtin_amdgcn_cvt_pk_fp8_f32)
    unsigned u = __builtin_amdgcn_cvt_pk_fp8_f32(e0, e1, 0, false);
    u = __builtin_amdgcn_cvt_pk_fp8_f32(e2, e3, u, true);
    return u;
#else
    return (unsigned)fp8_enc(e0) | ((unsigned)fp8_enc(e1) << 8) |
           ((unsigned)fp8_enc(e2) << 16) | ((unsigned)fp8_enc(e3) << 24);
#endif
}
__device__ __forceinline__ float fp8_dec1(unsigned char u) {
    unsigned bits = ((u & 0x80u) << 24) | ((u & 0x7Fu) << 20);
    return __uint_as_float(bits) * 0x1p+120f;
}
__device__ __forceinline__ f32x2 fp8_dec_lo(unsigned v) {
#if __has_builtin(__builtin_amdgcn_cvt_pk_f32_fp8)
    return __builtin_amdgcn_cvt_pk_f32_fp8(v, false);
#else
    f32x2 r; r.x = fp8_dec1(v & 0xFF); r.y = fp8_dec1((v >> 8) & 0xFF); return r;
#endif
}
__device__ __forceinline__ f32x2 fp8_dec_hi(unsigned v) {
#if __has_builtin(__builtin_amdgcn_cvt_pk_f32_fp8)
    return __builtin_amdgcn_cvt_pk_f32_fp8(v, true);
#else
    f32x2 r; r.x = fp8_dec1((v >> 16) & 0xFF); r.y = fp8_dec1(v >> 24); return r;
#endif
}

// ---- async global->LDS, 16 B per lane ----
#if defined(__has_builtin)
#if __has_builtin(__builtin_amdgcn_global_load_lds)
#define HAS_GLL 1
#endif
#endif
#if HAS_GLL
__device__ __forceinline__ void gll16(const void* g, void* l) {
    __builtin_amdgcn_global_load_lds(
        (__attribute__((address_space(1))) void*)(void*)g,
        (__attribute__((address_space(3))) void*)l, 16, 0, 0);
}
#endif

// ---------------------------------------------------------------------------
__global__ __launch_bounds__(256) void quant_x(const float* __restrict__ X,
                                               unsigned short* __restrict__ Xb) {
    int i = blockIdx.x * 256 + threadIdx.x;
    const float4 v = ((const float4*)X)[i];
    ushort4 o = { f2bf(v.x), f2bf(v.y), f2bf(v.z), f2bf(v.w) };
    ((ushort4*)Xb)[i] = o;
}

// W[k][n] fp32 -> Wt[z][n][k] bf16.  grid (24,24,4), block 256
__global__ __launch_bounds__(256) void quant_wt(
    const float* __restrict__ W0, const float* __restrict__ W1,
    const float* __restrict__ W2, const float* __restrict__ W3,
    unsigned short* __restrict__ Wt) {
    const float* W = (blockIdx.z == 0) ? W0 : (blockIdx.z == 1) ? W1
                   : (blockIdx.z == 2) ? W2 : W3;
    __shared__ unsigned short t[32][33];
    const int n0 = blockIdx.x * 32, k0 = blockIdx.y * 32;
    const int c = threadIdx.x & 31, r8 = threadIdx.x >> 5;
#pragma unroll
    for (int rr = 0; rr < 32; rr += 8) {
        int k = k0 + r8 + rr;
        t[c][r8 + rr] = f2bf(W[(size_t)k * E_DIM + n0 + c]);
    }
    __syncthreads();
    unsigned short* out = Wt + (size_t)blockIdx.z * E_DIM * E_DIM;
#pragma unroll
    for (int rr = 0; rr < 32; rr += 8) {
        int n = n0 + r8 + rr;
        out[(size_t)n * E_DIM + k0 + c] = t[r8 + rr][c];
    }
}

// ---------------------------------------------------------------------------
// Fused QKV GEMM, global_load_lds staging, tile 128x64, BK=64.
// grid (36, 16), block 256.  All outputs bf16 [h][s][64].
__global__ __launch_bounds__(256) void qkv_gemm(
    const unsigned short* __restrict__ Xb, const unsigned short* __restrict__ Wt,
    const float* __restrict__ bq, const float* __restrict__ bk, const float* __restrict__ bv,
    unsigned short* __restrict__ Qb, unsigned short* __restrict__ Kb,
    unsigned short* __restrict__ Vb) {
    __shared__ unsigned short As[128 * 64];
    __shared__ unsigned short Bs[64 * 64];
    const int n0 = blockIdx.x * 64;
    const int row0 = blockIdx.y * 128;
    const int tid = threadIdx.x;
    const int wave = tid >> 6, lane = tid & 63;
    const int wm = wave & 1, wn = wave >> 1;
    const int q = lane >> 4, c = lane & 15;
    const int lrow = lane >> 3, lk8 = (lane & 7) * 8;
    const unsigned short* Wb = Wt + (size_t)n0 * E_DIM;
    f32x4 acc[4][2] = {};
    for (int kt = 0; kt < E_DIM; kt += 64) {
        __syncthreads();
#if HAS_GLL
#pragma unroll
        for (int p = 0; p < 4; ++p)
            gll16(&Xb[(size_t)(row0 + p * 32 + wave * 8 + lrow) * E_DIM + kt + lk8],
                  &As[(p * 32 + wave * 8) * 64]);
#pragma unroll
        for (int p = 0; p < 2; ++p)
            gll16(&Wb[(size_t)(p * 32 + wave * 8 + lrow) * E_DIM + kt + lk8],
                  &Bs[(p * 32 + wave * 8) * 64]);
#else
        {
            uint4 ta[4], tb[2];
#pragma unroll
            for (int p = 0; p < 4; ++p)
                ta[p] = *(const uint4*)&Xb[(size_t)(row0 + p * 32 + wave * 8 + lrow) * E_DIM + kt + lk8];
#pragma unroll
            for (int p = 0; p < 2; ++p)
                tb[p] = *(const uint4*)&Wb[(size_t)(p * 32 + wave * 8 + lrow) * E_DIM + kt + lk8];
#pragma unroll
            for (int p = 0; p < 4; ++p) *(uint4*)&As[(p * 32 + wave * 8 + lrow) * 64 + lk8] = ta[p];
#pragma unroll
            for (int p = 0; p < 2; ++p) *(uint4*)&Bs[(p * 32 + wave * 8 + lrow) * 64 + lk8] = tb[p];
        }
#endif
        __syncthreads();
#pragma unroll
        for (int ks = 0; ks < 2; ++ks) {
            bf16x8 af[4], bfr[2];
#pragma unroll
            for (int mi = 0; mi < 4; ++mi)
                af[mi] = *(const bf16x8*)&As[(wm * 64 + mi * 16 + c) * 64 + ks * 32 + q * 8];
#pragma unroll
            for (int ni = 0; ni < 2; ++ni)
                bfr[ni] = *(const bf16x8*)&Bs[(wn * 32 + ni * 16 + c) * 64 + ks * 32 + q * 8];
#pragma unroll
            for (int mi = 0; mi < 4; ++mi)
#pragma unroll
                for (int ni = 0; ni < 2; ++ni)
                    acc[mi][ni] = __builtin_amdgcn_mfma_f32_16x16x32_bf16(
                        af[mi], bfr[ni], acc[mi][ni], 0, 0, 0);
        }
    }
    const int z = n0 / E_DIM;
    const int h = (n0 % E_DIM) >> 6;
    const float* bias = (z == 0) ? bq : (z == 1) ? bk : bv;
    unsigned short* outp = (z == 0) ? Qb : (z == 1) ? Kb : Vb;
    __syncthreads();
    unsigned short* Cs = As;
#pragma unroll
    for (int ni = 0; ni < 2; ++ni) {
        const int col = wn * 32 + ni * 16 + c;
        const float bb = bias[h * 64 + col];
#pragma unroll
        for (int mi = 0; mi < 4; ++mi)
#pragma unroll
            for (int r = 0; r < 4; ++r)
                Cs[(wm * 64 + mi * 16 + q * 4 + r) * 64 + col] = f2bf(acc[mi][ni][r] + bb);
    }
    __syncthreads();
#pragma unroll
    for (int pp = 0; pp < 4; ++pp) {
        int row = pp * 32 + (tid >> 3);
        *(uint4*)&outp[((size_t)h * S_LEN + row0 + row) * HD + (tid & 7) * 8] =
            *(const uint4*)&Cs[row * 64 + (tid & 7) * 8];
    }
}

// ---------------------------------------------------------------------------
// E = exp(QK^T/8) -> fp8.  SWAPPED operands (A=K, B=Q): D[m=j][n=i].
// grid (16 j-tiles(128), 32 i-tiles(64), 12 h), block 256.
__global__ __launch_bounds__(256) void score_exp(
    const unsigned short* __restrict__ Qb, const unsigned short* __restrict__ Kb,
    unsigned char* __restrict__ E) {
    const int h = blockIdx.z;
    const int i0 = blockIdx.y * 64, j0 = blockIdx.x * 128;
    const int tid = threadIdx.x;
    const int wave = tid >> 6, lane = tid & 63;
    const int q = lane >> 4, c = lane & 15;
    __shared__ unsigned short Qs[64 * 64];
    __shared__ unsigned short Ks[128 * 64];
    __shared__ unsigned char  Es[64 * 144];
    const unsigned short* Qh = Qb + (size_t)h * S_LEN * HD;
    const unsigned short* Kh = Kb + (size_t)h * S_LEN * HD;
    const int lrow = lane >> 3, lk8 = (lane & 7) * 8;
#if HAS_GLL
#pragma unroll
    for (int p = 0; p < 2; ++p)
        gll16(&Qh[(size_t)(i0 + p * 32 + wave * 8 + lrow) * HD + lk8],
              &Qs[(p * 32 + wave * 8) * 64]);
#pragma unroll
    for (int p = 0; p < 4; ++p)
        gll16(&Kh[(size_t)(j0 + p * 32 + wave * 8 + lrow) * HD + lk8],
              &Ks[(p * 32 + wave * 8) * 64]);
#else
    {
        uint4 tq[2], tk[4];
#pragma unroll
        for (int p = 0; p < 2; ++p)
            tq[p] = *(const uint4*)&Qh[(size_t)(i0 + p * 32 + wave * 8 + lrow) * HD + lk8];
#pragma unroll
        for (int p = 0; p < 4; ++p)
            tk[p] = *(const uint4*)&Kh[(size_t)(j0 + p * 32 + wave * 8 + lrow) * HD + lk8];
#pragma unroll
        for (int p = 0; p < 2; ++p) *(uint4*)&Qs[(p * 32 + wave * 8 + lrow) * 64 + lk8] = tq[p];
#pragma unroll
        for (int p = 0; p < 4; ++p) *(uint4*)&Ks[(p * 32 + wave * 8 + lrow) * 64 + lk8] = tk[p];
    }
#endif
    __syncthreads();
    f32x4 acc[2][4] = {};
#pragma unroll
    for (int dt = 0; dt < HD; dt += 32) {
        bf16x8 af[2], bq_[4];
#pragma unroll
        for (int jt = 0; jt < 2; ++jt)
            af[jt] = *(const bf16x8*)&Ks[(wave * 32 + jt * 16 + c) * 64 + dt + q * 8];
#pragma unroll
        for (int it = 0; it < 4; ++it)
            bq_[it] = *(const bf16x8*)&Qs[(it * 16 + c) * 64 + dt + q * 8];
#pragma unroll
        for (int jt = 0; jt < 2; ++jt)
#pragma unroll
            for (int it = 0; it < 4; ++it)
                acc[jt][it] = __builtin_amdgcn_mfma_f32_16x16x32_bf16(
                    af[jt], bq_[it], acc[jt][it], 0, 0, 0);
    }
#pragma unroll
    for (int jt = 0; jt < 2; ++jt)
#pragma unroll
        for (int it = 0; it < 4; ++it) {
            float e0 = __expf(acc[jt][it][0] * 0.125f);
            float e1 = __expf(acc[jt][it][1] * 0.125f);
            float e2 = __expf(acc[jt][it][2] * 0.125f);
            float e3 = __expf(acc[jt][it][3] * 0.125f);
            *(unsigned*)&Es[(it * 16 + c) * 144 + wave * 32 + jt * 16 + q * 4] =
                fp8_pack4(e0, e1, e2, e3);
        }
    __syncthreads();
    {   // coalesced full-line E stores
        const int row = tid >> 2, off = (tid & 3) * 32;
        uint4 v0 = *(const uint4*)&Es[row * 144 + off];
        uint4 v1 = *(const uint4*)&Es[row * 144 + off + 16];
        unsigned char* dst = E + ((size_t)h * S_LEN + i0 + row) * S_LEN + j0 + off;
        *(uint4*)dst = v0;
        *(uint4*)(dst + 16) = v1;
    }
}

// ---------------------------------------------------------------------------
// Cooperative Sinkhorn: grid 768 (64 chunks x 12 h), block 256, E chunk
// (32 rows x 2048) pinned in VGPRs across all 3 iterations.
//   per iter: col partials -> tp; grid.sync; b-slice update; grid.sync;
//             (it<2) restage b -> a = mu/(E.b)
// tail: write a3; Vt[h][d][j] = fp8(b3[j] * V[h][j][d]) for own j-slice.
#define BPAD(j) ((j) + ((j) >> 4))
__global__ __launch_bounds__(256, 3) void sinkhorn_all(
    const unsigned char* __restrict__ E, float* bvec, float* aout,
    float* tpart, const unsigned short* __restrict__ Vb,
    unsigned char* __restrict__ Vt) {
    cg::grid_group gg = cg::this_grid();
    __shared__ float smem[4 * 64 * 20];         // 20.5 KB, multi-purpose
    const int bid = blockIdx.x;
    const int h = bid / NCH2, chunk = bid % NCH2;
    const int tid = threadIdx.x, wave = tid >> 6, lane = tid & 63;
    const int jA = lane * 16, jB = 1024 + jA;
    const unsigned char* gbase = E + ((size_t)h * S_LEN + chunk * CH2) * S_LEN;
    uint4 eA[8], eB[8];                         // wave's 8 rows, 32 j/lane
#pragma unroll
    for (int rr = 0; rr < 8; ++rr) {
        const unsigned char* er = gbase + (size_t)(wave * 8 + rr) * S_LEN;
        eA[rr] = *(const uint4*)&er[jA];
        eB[rr] = *(const uint4*)&er[jB];
    }
    // a1 = mu / rowsum(E)
    float a_r[8];
#pragma unroll
    for (int rr = 0; rr < 8; ++rr) {
        float s = 0.f;
        unsigned wA[4] = {eA[rr].x, eA[rr].y, eA[rr].z, eA[rr].w};
        unsigned wB[4] = {eB[rr].x, eB[rr].y, eB[rr].z, eB[rr].w};
#pragma unroll
        for (int m = 0; m < 4; ++m) {
            f32x2 lo = fp8_dec_lo(wA[m]), hi = fp8_dec_hi(wA[m]);
            s += (lo.x + lo.y) + (hi.x + hi.y);
            lo = fp8_dec_lo(wB[m]); hi = fp8_dec_hi(wB[m]);
            s += (lo.x + lo.y) + (hi.x + hi.y);
        }
#pragma unroll
        for (int off = 32; off; off >>= 1) s += __shfl_xor(s, off, 64);
        a_r[rr] = MU / s;
    }
    for (int it = 0; it < 3; ++it) {
        // column partials from registers, cross-wave combine per j-half
#pragma unroll
        for (int half = 0; half < 2; ++half) {
            float acc[16] = {};
#pragma unroll
            for (int rr = 0; rr < 8; ++rr) {
                const uint4 e = half ? eB[rr] : eA[rr];
                const float ar = a_r[rr];
                unsigned w4[4] = {e.x, e.y, e.z, e.w};
#pragma unroll
                for (int m = 0; m < 4; ++m) {
                    f32x2 lo = fp8_dec_lo(w4[m]), hi = fp8_dec_hi(w4[m]);
                    acc[m*4+0] += lo.x * ar; acc[m*4+1] += lo.y * ar;
                    acc[m*4+2] += hi.x * ar; acc[m*4+3] += hi.y * ar;
                }
            }
#pragma unroll
            for (int s4 = 0; s4 < 4; ++s4) {
                float4 v = {acc[s4*4], acc[s4*4+1], acc[s4*4+2], acc[s4*4+3]};
                *(float4*)&smem[wave * 1280 + lane * 20 + s4 * 4] = v;
            }
            __syncthreads();
            {
                const int run = tid >> 2, m0 = (tid & 3) * 4;
                float4 s0 = *(const float4*)&smem[0 * 1280 + run * 20 + m0];
                float4 s1 = *(const float4*)&smem[1 * 1280 + run * 20 + m0];
                float4 s2 = *(const float4*)&smem[2 * 1280 + run * 20 + m0];
                float4 s3 = *(const float4*)&smem[3 * 1280 + run * 20 + m0];
                float4 o = {(s0.x + s1.x) + (s2.x + s3.x), (s0.y + s1.y) + (s2.y + s3.y),
                            (s0.z + s1.z) + (s2.z + s3.z), (s0.w + s1.w) + (s2.w + s3.w)};
                *(float4*)&tpart[((size_t)h * NCH2 + chunk) * S_LEN + half * 1024 + tid * 4] = o;
            }
            __syncthreads();
        }
        gg.sync();
        // b-update: this block owns j-slice [chunk*32, +32) of head h
        {
            const int jj = chunk * CH2 + (tid & 31);
            const int c0 = (tid >> 5) * 8;
            float s = 0.f;
#pragma unroll
            for (int cc = 0; cc < 8; ++cc)
                s += tpart[((size_t)h * NCH2 + c0 + cc) * S_LEN + jj];
            smem[(tid >> 5) * 32 + (tid & 31)] = s;
            __syncthreads();
            if (tid < 32) {
                float tot = 0.f;
#pragma unroll
                for (int cc = 0; cc < 8; ++cc) tot += smem[cc * 32 + tid];
                bvec[(size_t)h * S_LEN + chunk * CH2 + tid] = MU / tot;
            }
            __syncthreads();
        }
        gg.sync();
        if (it < 2) {       // a = mu / (E.b) with fresh b
            const float* bg = bvec + (size_t)h * S_LEN;
#pragma unroll
            for (int p = 0; p < 8; ++p) {
                int j = p * 256 + tid;
                smem[BPAD(j)] = bg[j];
            }
            __syncthreads();
            float bA[16], bB[16];
#pragma unroll
            for (int m = 0; m < 16; ++m) { bA[m] = smem[BPAD(jA + m)]; bB[m] = smem[BPAD(jB + m)]; }
#pragma unroll
            for (int rr = 0; rr < 8; ++rr) {
                float s = 0.f;
                unsigned wA[4] = {eA[rr].x, eA[rr].y, eA[rr].z, eA[rr].w};
                unsigned wB[4] = {eB[rr].x, eB[rr].y, eB[rr].z, eB[rr].w};
#pragma unroll
                for (int m = 0; m < 4; ++m) {
                    f32x2 lo = fp8_dec_lo(wA[m]), hi = fp8_dec_hi(wA[m]);
                    s += lo.x * bA[m*4] + lo.y * bA[m*4+1] + hi.x * bA[m*4+2] + hi.y * bA[m*4+3];
                    lo = fp8_dec_lo(wB[m]); hi = fp8_dec_hi(wB[m]);
                    s += lo.x * bB[m*4] + lo.y * bB[m*4+1] + hi.x * bB[m*4+2] + hi.y * bB[m*4+3];
                }
#pragma unroll
                for (int off = 32; off; off >>= 1) s += __shfl_xor(s, off, 64);
                a_r[rr] = MU / s;
            }
            __syncthreads();
        }
    }
    // write a3 (every lane holds all 8 values after butterfly)
    if (lane == 0) {
#pragma unroll
        for (int rr = 0; rr < 8; ++rr)
            aout[(size_t)h * S_LEN + chunk * CH2 + wave * 8 + rr] = a_r[rr];
    }
    // Vt[h][d][j-slice] = fp8(b3[j] * V[h][j][d]) via LDS transpose
    {
        unsigned char* tv = (unsigned char*)smem;   // [64][80]
        const int jrow = tid >> 3, dc = (tid & 7) * 8;
        const int j0 = chunk * CH2;
        float bj = bvec[(size_t)h * S_LEN + j0 + jrow];
        uint4 v8 = *(const uint4*)&Vb[((size_t)h * S_LEN + j0 + jrow) * HD + dc];
        const unsigned short* vs = (const unsigned short*)&v8;
#pragma unroll
        for (int k = 0; k < 8; ++k)
            tv[(dc + k) * 80 + jrow] = fp8_enc(bf2f(vs[k]) * bj);
        __syncthreads();
        if (tid < 128) {
            const int d = tid >> 1, jc = (tid & 1) * 16;
            *(uint4*)&Vt[((size_t)h * HD + d) * S_LEN + j0 + jc] = *(const uint4*)&tv[d * 80 + jc];
        }
    }
}

// ---------------------------------------------------------------------------
// ctx[i][h*64+d] = a_i*n * sum_j E[h][i][j]*V't[h][d][j].  fp8 MFMA.
// grid (64, 12), block 256.
__global__ __launch_bounds__(256) void attn_av(
    const unsigned char* __restrict__ E, const float* __restrict__ a,
    const unsigned char* __restrict__ Vt, unsigned short* __restrict__ ctxb) {
    const int h = blockIdx.y;
    const int wave = threadIdx.x >> 6, lane = threadIdx.x & 63;
    const int q = lane >> 4, c = lane & 15;
    const int i0 = blockIdx.x * 32;
    const unsigned char* e0 = E + (size_t)h * S_LEN * S_LEN + (size_t)(i0 + c) * S_LEN;
    const unsigned char* e1 = e0 + (size_t)16 * S_LEN;
    const unsigned char* Vh = Vt + (size_t)h * HD * S_LEN;
    const int jb = wave * 512;
    f32x4 acc[2][4] = {};
    i64_t eN[2][2], vN[4][2];
#pragma unroll
    for (int kk = 0; kk < 2; ++kk) {
        eN[0][kk] = *(const i64_t*)&e0[jb + kk * 32 + q * 8];
        eN[1][kk] = *(const i64_t*)&e1[jb + kk * 32 + q * 8];
#pragma unroll
        for (int s = 0; s < 4; ++s)
            vN[s][kk] = *(const i64_t*)&Vh[(size_t)(s * 16 + c) * S_LEN + jb + kk * 32 + q * 8];
    }
    for (int jt = jb; jt < jb + 512; jt += 64) {
        i64_t eC[2][2], vC[4][2];
#pragma unroll
        for (int kk = 0; kk < 2; ++kk) {
            eC[0][kk] = eN[0][kk]; eC[1][kk] = eN[1][kk];
#pragma unroll
            for (int s = 0; s < 4; ++s) vC[s][kk] = vN[s][kk];
        }
        if (jt + 64 < jb + 512) {
            const int jn = jt + 64;
#pragma unroll
            for (int kk = 0; kk < 2; ++kk) {
                eN[0][kk] = *(const i64_t*)&e0[jn + kk * 32 + q * 8];
                eN[1][kk] = *(const i64_t*)&e1[jn + kk * 32 + q * 8];
#pragma unroll
                for (int s = 0; s < 4; ++s)
                    vN[s][kk] = *(const i64_t*)&Vh[(size_t)(s * 16 + c) * S_LEN + jn + kk * 32 + q * 8];
            }
        }
#pragma unroll
        for (int kk = 0; kk < 2; ++kk)
#pragma unroll
            for (int it = 0; it < 2; ++it)
#pragma unroll
                for (int s = 0; s < 4; ++s)
                    acc[it][s] = __builtin_amdgcn_mfma_f32_16x16x32_fp8_fp8(
                        eC[it][kk], vC[s][kk], acc[it][s], 0, 0, 0);
    }
    __shared__ float lred[3][2][16][64];
    if (wave != 0) {
#pragma unroll
        for (int it = 0; it < 2; ++it)
#pragma unroll
            for (int s = 0; s < 4; ++s)
#pragma unroll
                for (int r = 0; r < 4; ++r)
                    lred[wave - 1][it][s * 4 + r][lane] = acc[it][s][r];
    }
    __syncthreads();
    if (wave == 0) {
#pragma unroll
        for (int it = 0; it < 2; ++it) {
            float ais[4];
#pragma unroll
            for (int r = 0; r < 4; ++r)
                ais[r] = a[(size_t)h * S_LEN + i0 + it * 16 + q * 4 + r] * 2048.f;
#pragma unroll
            for (int s = 0; s < 4; ++s)
#pragma unroll
                for (int r = 0; r < 4; ++r) {
                    float v = acc[it][s][r] +
                              ((lred[0][it][s * 4 + r][lane] + lred[1][it][s * 4 + r][lane]) +
                               lred[2][it][s * 4 + r][lane]);
                    ctxb[(size_t)(i0 + it * 16 + q * 4 + r) * E_DIM + h * 64 + s * 16 + c] =
                        f2bf(v * ais[r]);
                }
        }
    }
}

// ---------------------------------------------------------------------------
// Y = ctx @ Wo + bo + X (fp32), gll staging, tile 128x64.  grid (12, 16), 256
__global__ __launch_bounds__(256) void out_gemm(
    const unsigned short* __restrict__ ctxb, const unsigned short* __restrict__ Wt,
    const float* __restrict__ bo, const float* __restrict__ X, float* __restrict__ Y) {
    __shared__ unsigned short As[128 * 64];
    __shared__ unsigned short Bs[64 * 64];
    __shared__ float Csf[64 * 64];
    const int n0 = blockIdx.x * 64;
    const int row0 = blockIdx.y * 128;
    const int tid = threadIdx.x;
    const int wave = tid >> 6, lane = tid & 63;
    const int wm = wave & 1, wn = wave >> 1;
    const int q = lane >> 4, c = lane & 15;
    const int lrow = lane >> 3, lk8 = (lane & 7) * 8;
    const unsigned short* Wo3 = Wt + (size_t)3 * E_DIM * E_DIM + (size_t)n0 * E_DIM;
    f32x4 acc[4][2] = {};
    for (int kt = 0; kt < E_DIM; kt += 64) {
        __syncthreads();
#if HAS_GLL
#pragma unroll
        for (int p = 0; p < 4; ++p)
            gll16(&ctxb[(size_t)(row0 + p * 32 + wave * 8 + lrow) * E_DIM + kt + lk8],
                  &As[(p * 32 + wave * 8) * 64]);
#pragma unroll
        for (int p = 0; p < 2; ++p)
            gll16(&Wo3[(size_t)(p * 32 + wave * 8 + lrow) * E_DIM + kt + lk8],
                  &Bs[(p * 32 + wave * 8) * 64]);
#else
        {
            uint4 ta[4], tb[2];
#pragma unroll
            for (int p = 0; p < 4; ++p)
                ta[p] = *(const uint4*)&ctxb[(size_t)(row0 + p * 32 + wave * 8 + lrow) * E_DIM + kt + lk8];
#pragma unroll
            for (int p = 0; p < 2; ++p)
                tb[p] = *(const uint4*)&Wo3[(size_t)(p * 32 + wave * 8 + lrow) * E_DIM + kt + lk8];
#pragma unroll
            for (int p = 0; p < 4; ++p) *(uint4*)&As[(p * 32 + wave * 8 + lrow) * 64 + lk8] = ta[p];
#pragma unroll
            for (int p = 0; p < 2; ++p) *(uint4*)&Bs[(p * 32 + wave * 8 + lrow) * 64 + lk8] = tb[p];
        }
#endif
        __syncthreads();
#pragma unroll
        for (int ks = 0; ks < 2; ++ks) {
            bf16x8 af[4], bfr[2];
#pragma unroll
            for (int mi = 0; mi < 4; ++mi)
                af[mi] = *(const bf16x8*)&As[(wm * 64 + mi * 16 + c) * 64 + ks * 32 + q * 8];
#pragma unroll
            for (int ni = 0; ni < 2; ++ni)
                bfr[ni] = *(const bf16x8*)&Bs[(wn * 32 + ni * 16 + c) * 64 + ks * 32 + q * 8];
#pragma unroll
            for (int mi = 0; mi < 4; ++mi)
#pragma unroll
                for (int ni = 0; ni < 2; ++ni)
                    acc[mi][ni] = __builtin_amdgcn_mfma_f32_16x16x32_bf16(
                        af[mi], bfr[ni], acc[mi][ni], 0, 0, 0);
        }
    }
#pragma unroll
    for (int pp = 0; pp < 2; ++pp) {
        __syncthreads();
        if (wm == pp) {
#pragma unroll
            for (int mi = 0; mi < 4; ++mi)
#pragma unroll
                for (int ni = 0; ni < 2; ++ni)
#pragma unroll
                    for (int r = 0; r < 4; ++r)
                        Csf[(mi * 16 + q * 4 + r) * 64 + wn * 32 + ni * 16 + c] = acc[mi][ni][r];
        }
        __syncthreads();
#pragma unroll
        for (int sp = 0; sp < 4; ++sp) {
            int row = sp * 16 + (tid >> 4);
            int col = (tid & 15) * 4;
            int grow = row0 + pp * 64 + row;
            float4 v = *(const float4*)&Csf[row * 64 + col];
            const float4 xr = *(const float4*)&X[(size_t)grow * E_DIM + n0 + col];
            const float4 bb = *(const float4*)&bo[n0 + col];
            float4 o = {v.x + bb.x + xr.x, v.y + bb.y + xr.y,
                        v.z + bb.z + xr.z, v.w + bb.w + xr.w};
            *(float4*)&Y[(size_t)grow * E_DIM + n0 + col] = o;
        }
    }
}

// ---------------------------------------------------------------------------
// LayerNorm per row.  grid (S), block 256
__global__ __launch_bounds__(256) void layernorm(
    const float* __restrict__ Y, const float* __restrict__ g,
    const float* __restrict__ b, float* __restrict__ out) {
    __shared__ float red[4];
    const int srow = blockIdx.x;
    const float* yr = Y + (size_t)srow * E_DIM;
    const int t = threadIdx.x;
    float xs[3];
    float sum = 0.f;
#pragma unroll
    for (int r = 0; r < 3; ++r) { xs[r] = yr[t + r * 256]; sum += xs[r]; }
#pragma unroll
    for (int off = 32; off; off >>= 1) sum += __shfl_down(sum, off, 64);
    if ((t & 63) == 0) red[t >> 6] = sum;
    __syncthreads();
    sum = red[0] + red[1] + red[2] + red[3];
    const float mu = sum * (1.f / 768.f);
    float vs = 0.f;
#pragma unroll
    for (int r = 0; r < 3; ++r) { float d = xs[r] - mu; vs += d * d; }
    __syncthreads();
#pragma unroll
    for (int off = 32; off; off >>= 1) vs += __shfl_down(vs, off, 64);
    if ((t & 63) == 0) red[t >> 6] = vs;
    __syncthreads();
    vs = red[0] + red[1] + red[2] + red[3];
    const float inv = rsqrtf(vs * (1.f / 768.f) + LN_EPS);
#pragma unroll
    for (int r = 0; r < 3; ++r) {
        int c = t + r * 256;
        out[(size_t)srow * E_DIM + c] = g[c] * (xs[r] - mu) * inv + b[c];
    }
}

// ---------------------------------------------------------------------------
extern "C" void kernel_launch(void* const* d_in, const int* in_sizes, int n_in,
                              void* d_out, int out_size, void* d_ws, size_t ws_size,
                              hipStream_t stream) {
    const float* X    = (const float*)d_in[0];
    const float* Wq   = (const float*)d_in[1];
    const float* bq   = (const float*)d_in[2];
    const float* Wk   = (const float*)d_in[3];
    const float* bk   = (const float*)d_in[4];
    const float* Wv   = (const float*)d_in[5];
    const float* bv   = (const float*)d_in[6];
    const float* Wo   = (const float*)d_in[7];
    const float* bo   = (const float*)d_in[8];
    const float* ln_g = (const float*)d_in[9];
    const float* ln_b = (const float*)d_in[10];
    float* out = (float*)d_out;

    char* p = (char*)d_ws;
    auto alloc = [&](size_t bytes) { char* r = p; p += (bytes + 255) & ~(size_t)255; return r; };
    unsigned short* Xb   = (unsigned short*)alloc((size_t)S_LEN * E_DIM * 2);
    unsigned short* Wt   = (unsigned short*)alloc((size_t)4 * E_DIM * E_DIM * 2);
    unsigned short* Qb   = (unsigned short*)alloc((size_t)NH * S_LEN * HD * 2);
    unsigned short* Kb   = (unsigned short*)alloc((size_t)NH * S_LEN * HD * 2);
    unsigned short* Vb   = (unsigned short*)alloc((size_t)NH * S_LEN * HD * 2);
    unsigned char*  E    = (unsigned char*)alloc((size_t)NH * S_LEN * S_LEN);   // 48 MB fp8
    float*          av   = (float*)alloc((size_t)NH * S_LEN * 4);
    float*          bv_  = (float*)alloc((size_t)NH * S_LEN * 4);
    float*          tp   = (float*)alloc((size_t)NH * NCH2 * S_LEN * 4);        // 6 MB
    unsigned char*  Vt   = (unsigned char*)alloc((size_t)NH * HD * S_LEN);
    unsigned short* ctxb = (unsigned short*)alloc((size_t)S_LEN * E_DIM * 2);
    float*          Y    = (float*)alloc((size_t)S_LEN * E_DIM * 4);

    quant_x<<<S_LEN * E_DIM / 1024, 256, 0, stream>>>(X, Xb);
    quant_wt<<<dim3(24, 24, 4), 256, 0, stream>>>(Wq, Wk, Wv, Wo, Wt);
    qkv_gemm<<<dim3(36, 16), 256, 0, stream>>>(Xb, Wt, bq, bk, bv, Qb, Kb, Vb);
    score_exp<<<dim3(16, 32, NH), 256, 0, stream>>>(Qb, Kb, E);

    {   // full Sinkhorn (3 iterations) in one cooperative launch
        const unsigned char* Ec = E;
        const unsigned short* Vbc = Vb;
        void* args[] = { (void*)&Ec, (void*)&bv_, (void*)&av, (void*)&tp,
                         (void*)&Vbc, (void*)&Vt };
        hipLaunchCooperativeKernel(sinkhorn_all, dim3(NCH2 * NH), dim3(256),
                                   args, 0, stream);
    }

    attn_av<<<dim3(S_LEN / 32, NH), 256, 0, stream>>>(E, av, Vt, ctxb);
    out_gemm<<<dim3(12, 16), 256, 0, stream>>>(ctxb, Wt, bo, X, Y);
    layernorm<<<S_LEN, 256, 0, stream>>>(Y, ln_g, ln_b, out);
}

// Round 13
// 239.182 us; speedup vs baseline: 4.3794x; 4.3794x over previous
//
#include <hip/hip_runtime.h>
#include <math.h>

#define S_LEN 2048
#define E_DIM 768
#define NH    12
#define HD    64
#define MU    (1.0f/2048.0f)
#define LN_EPS 1e-12f
#define CH    16            // sink_pass chunk rows
#define NCH   (S_LEN/CH)    // 128 chunks

typedef __attribute__((ext_vector_type(8))) short bf16x8;   // 8 bf16 (4 VGPRs)
typedef __attribute__((ext_vector_type(4))) float f32x4;    // MFMA accumulator
typedef __attribute__((ext_vector_type(2))) float f32x2;
typedef long i64_t;                                          // 8 fp8 (2 VGPRs)

__device__ __forceinline__ unsigned short f2bf(float f) {   // RNE fp32->bf16
    unsigned u = __float_as_uint(f);
    u += 0x7fff + ((u >> 16) & 1);
    return (unsigned short)(u >> 16);
}
__device__ __forceinline__ float bf2f(unsigned short h) {
    return __uint_as_float(((unsigned)h) << 16);
}

// ---- fp8 e4m3 (OCP) helpers ----
__device__ __forceinline__ unsigned char fp8_enc(float f) {
#if __has_builtin(__builtin_amdgcn_cvt_pk_fp8_f32)
    return (unsigned char)(__builtin_amdgcn_cvt_pk_fp8_f32(f, f, 0, false) & 0xFF);
#else
    float m = fminf(fabsf(f), 448.f) * 0x1p-120f;
    unsigned b = __float_as_uint(m);
    unsigned s = (__float_as_uint(f) >> 24) & 0x80u;
    b += 0x7FFFFu + ((b >> 20) & 1u);
    return (unsigned char)(s | ((b >> 20) & 0x7Fu));
#endif
}
// pack 4 floats -> 4 fp8 bytes in one dword
__device__ __forceinline__ unsigned fp8_pack4(float e0, float e1, float e2, float e3) {
#if __has_builtin(__builtin_amdgcn_cvt_pk_fp8_f32)
    unsigned u = __builtin_amdgcn_cvt_pk_fp8_f32(e0, e1, 0, false);
    u = __builtin_amdgcn_cvt_pk_fp8_f32(e2, e3, u, true);
    return u;
#else
    return (unsigned)fp8_enc(e0) | ((unsigned)fp8_enc(e1) << 8) |
           ((unsigned)fp8_enc(e2) << 16) | ((unsigned)fp8_enc(e3) << 24);
#endif
}
__device__ __forceinline__ float fp8_dec1(unsigned char u) {
    unsigned bits = ((u & 0x80u) << 24) | ((u & 0x7Fu) << 20);
    return __uint_as_float(bits) * 0x1p+120f;
}
__device__ __forceinline__ f32x2 fp8_dec_lo(unsigned v) {
#if __has_builtin(__builtin_amdgcn_cvt_pk_f32_fp8)
    return __builtin_amdgcn_cvt_pk_f32_fp8(v, false);
#else
    f32x2 r; r.x = fp8_dec1(v & 0xFF); r.y = fp8_dec1((v >> 8) & 0xFF); return r;
#endif
}
__device__ __forceinline__ f32x2 fp8_dec_hi(unsigned v) {
#if __has_builtin(__builtin_amdgcn_cvt_pk_f32_fp8)
    return __builtin_amdgcn_cvt_pk_f32_fp8(v, true);
#else
    f32x2 r; r.x = fp8_dec1((v >> 16) & 0xFF); r.y = fp8_dec1(v >> 24); return r;
#endif
}

// ---- async global->LDS, 16 B per lane (dest = wave-uniform base + lane*16) ----
#if defined(__has_builtin)
#if __has_builtin(__builtin_amdgcn_global_load_lds)
#define HAS_GLL 1
#endif
#endif
#if HAS_GLL
__device__ __forceinline__ void gll16(const void* g, void* l) {
    __builtin_amdgcn_global_load_lds(
        (__attribute__((address_space(1))) void*)(void*)g,
        (__attribute__((address_space(3))) void*)l, 16, 0, 0);
}
#endif

// ---------------------------------------------------------------------------
// Merged preprocessing: X fp32->bf16 (blocks 0..1535) + 4x W fp32->bf16^T
// (blocks 1536..3839: 4 matrices x 576 32x32-tiles).  block 256.
__global__ __launch_bounds__(256) void quant_all(
    const float* __restrict__ X, unsigned short* __restrict__ Xb,
    const float* __restrict__ W0, const float* __restrict__ W1,
    const float* __restrict__ W2, const float* __restrict__ W3,
    unsigned short* __restrict__ Wt) {
    const int b = blockIdx.x;
    if (b < 1536) {                 // X quant: one float4 per thread
        int i = b * 256 + threadIdx.x;
        const float4 v = ((const float4*)X)[i];
        ushort4 o = { f2bf(v.x), f2bf(v.y), f2bf(v.z), f2bf(v.w) };
        ((ushort4*)Xb)[i] = o;
        return;
    }
    const int wb = b - 1536;
    const int z = wb / 576, t = wb % 576;
    const float* W = (z == 0) ? W0 : (z == 1) ? W1 : (z == 2) ? W2 : W3;
    __shared__ unsigned short tsm[32][33];
    const int n0 = (t % 24) * 32, k0 = (t / 24) * 32;
    const int c = threadIdx.x & 31, r8 = threadIdx.x >> 5;
#pragma unroll
    for (int rr = 0; rr < 32; rr += 8) {
        int k = k0 + r8 + rr;
        tsm[c][r8 + rr] = f2bf(W[(size_t)k * E_DIM + n0 + c]);
    }
    __syncthreads();
    unsigned short* out = Wt + (size_t)z * E_DIM * E_DIM;
#pragma unroll
    for (int rr = 0; rr < 32; rr += 8) {
        int n = n0 + r8 + rr;
        out[(size_t)n * E_DIM + k0 + c] = tsm[r8 + rr][c];
    }
}

// ---------------------------------------------------------------------------
// Fused QKV GEMM, global_load_lds staging, tile 128x64, BK=64.
// grid (36 n-tiles, 16 row-tiles), block 256.  All outputs bf16 [h][s][64].
__global__ __launch_bounds__(256) void qkv_gemm(
    const unsigned short* __restrict__ Xb, const unsigned short* __restrict__ Wt,
    const float* __restrict__ bq, const float* __restrict__ bk, const float* __restrict__ bv,
    unsigned short* __restrict__ Qb, unsigned short* __restrict__ Kb,
    unsigned short* __restrict__ Vb) {
    __shared__ unsigned short As[128 * 64];     // unpadded: required by gll
    __shared__ unsigned short Bs[64 * 64];
    const int n0 = blockIdx.x * 64;
    const int row0 = blockIdx.y * 128;
    const int tid = threadIdx.x;
    const int wave = tid >> 6, lane = tid & 63;
    const int wm = wave & 1, wn = wave >> 1;
    const int q = lane >> 4, c = lane & 15;
    const int lrow = lane >> 3, lk8 = (lane & 7) * 8;
    const unsigned short* Wb = Wt + (size_t)n0 * E_DIM;
    f32x4 acc[4][2] = {};
    for (int kt = 0; kt < E_DIM; kt += 64) {
        __syncthreads();
#if HAS_GLL
#pragma unroll
        for (int p = 0; p < 4; ++p)
            gll16(&Xb[(size_t)(row0 + p * 32 + wave * 8 + lrow) * E_DIM + kt + lk8],
                  &As[(p * 32 + wave * 8) * 64]);
#pragma unroll
        for (int p = 0; p < 2; ++p)
            gll16(&Wb[(size_t)(p * 32 + wave * 8 + lrow) * E_DIM + kt + lk8],
                  &Bs[(p * 32 + wave * 8) * 64]);
#else
        {
            uint4 ta[4], tb[2];
#pragma unroll
            for (int p = 0; p < 4; ++p)
                ta[p] = *(const uint4*)&Xb[(size_t)(row0 + p * 32 + wave * 8 + lrow) * E_DIM + kt + lk8];
#pragma unroll
            for (int p = 0; p < 2; ++p)
                tb[p] = *(const uint4*)&Wb[(size_t)(p * 32 + wave * 8 + lrow) * E_DIM + kt + lk8];
#pragma unroll
            for (int p = 0; p < 4; ++p) *(uint4*)&As[(p * 32 + wave * 8 + lrow) * 64 + lk8] = ta[p];
#pragma unroll
            for (int p = 0; p < 2; ++p) *(uint4*)&Bs[(p * 32 + wave * 8 + lrow) * 64 + lk8] = tb[p];
        }
#endif
        __syncthreads();
#pragma unroll
        for (int ks = 0; ks < 2; ++ks) {
            bf16x8 af[4], bfr[2];
#pragma unroll
            for (int mi = 0; mi < 4; ++mi)
                af[mi] = *(const bf16x8*)&As[(wm * 64 + mi * 16 + c) * 64 + ks * 32 + q * 8];
#pragma unroll
            for (int ni = 0; ni < 2; ++ni)
                bfr[ni] = *(const bf16x8*)&Bs[(wn * 32 + ni * 16 + c) * 64 + ks * 32 + q * 8];
#pragma unroll
            for (int mi = 0; mi < 4; ++mi)
#pragma unroll
                for (int ni = 0; ni < 2; ++ni)
                    acc[mi][ni] = __builtin_amdgcn_mfma_f32_16x16x32_bf16(
                        af[mi], bfr[ni], acc[mi][ni], 0, 0, 0);
        }
    }
    const int z = n0 / E_DIM;
    const int h = (n0 % E_DIM) >> 6;
    const float* bias = (z == 0) ? bq : (z == 1) ? bk : bv;
    unsigned short* outp = (z == 0) ? Qb : (z == 1) ? Kb : Vb;
    __syncthreads();
    unsigned short* Cs = As;                    // reuse 16 KB for repack
#pragma unroll
    for (int ni = 0; ni < 2; ++ni) {
        const int col = wn * 32 + ni * 16 + c;
        const float bb = bias[h * 64 + col];
#pragma unroll
        for (int mi = 0; mi < 4; ++mi)
#pragma unroll
            for (int r = 0; r < 4; ++r)
                Cs[(wm * 64 + mi * 16 + q * 4 + r) * 64 + col] = f2bf(acc[mi][ni][r] + bb);
    }
    __syncthreads();
#pragma unroll
    for (int pp = 0; pp < 4; ++pp) {
        int row = pp * 32 + (tid >> 3);
        *(uint4*)&outp[((size_t)h * S_LEN + row0 + row) * HD + (tid & 7) * 8] =
            *(const uint4*)&Cs[row * 64 + (tid & 7) * 8];
    }
}

// ---------------------------------------------------------------------------
// E = exp(QK^T/8) -> fp8.  SWAPPED operands (A=K, B=Q): D[m=j][n=i].
// grid (16 j-tiles(128), 32 i-tiles(64), 12 h), block 256.
__global__ __launch_bounds__(256) void score_exp(
    const unsigned short* __restrict__ Qb, const unsigned short* __restrict__ Kb,
    unsigned char* __restrict__ E, float* __restrict__ rp) {
    const int h = blockIdx.z;
    const int i0 = blockIdx.y * 64, j0 = blockIdx.x * 128;
    const int tid = threadIdx.x;
    const int wave = tid >> 6, lane = tid & 63;
    const int q = lane >> 4, c = lane & 15;
    __shared__ unsigned short Qs[64 * 64];
    __shared__ unsigned short Ks[128 * 64];
    __shared__ unsigned char  Es[64 * 144];     // row stride 144 B (pad: 2-way max)
    __shared__ float red[4][64];
    const unsigned short* Qh = Qb + (size_t)h * S_LEN * HD;
    const unsigned short* Kh = Kb + (size_t)h * S_LEN * HD;
    const int lrow = lane >> 3, lk8 = (lane & 7) * 8;
#if HAS_GLL
#pragma unroll
    for (int p = 0; p < 2; ++p)
        gll16(&Qh[(size_t)(i0 + p * 32 + wave * 8 + lrow) * HD + lk8],
              &Qs[(p * 32 + wave * 8) * 64]);
#pragma unroll
    for (int p = 0; p < 4; ++p)
        gll16(&Kh[(size_t)(j0 + p * 32 + wave * 8 + lrow) * HD + lk8],
              &Ks[(p * 32 + wave * 8) * 64]);
#else
    {
        uint4 tq[2], tk[4];
#pragma unroll
        for (int p = 0; p < 2; ++p)
            tq[p] = *(const uint4*)&Qh[(size_t)(i0 + p * 32 + wave * 8 + lrow) * HD + lk8];
#pragma unroll
        for (int p = 0; p < 4; ++p)
            tk[p] = *(const uint4*)&Kh[(size_t)(j0 + p * 32 + wave * 8 + lrow) * HD + lk8];
#pragma unroll
        for (int p = 0; p < 2; ++p) *(uint4*)&Qs[(p * 32 + wave * 8 + lrow) * 64 + lk8] = tq[p];
#pragma unroll
        for (int p = 0; p < 4; ++p) *(uint4*)&Ks[(p * 32 + wave * 8 + lrow) * 64 + lk8] = tk[p];
    }
#endif
    __syncthreads();
    f32x4 acc[2][4] = {};                       // [jt][it]; wave covers j = wave*32 + jt*16
#pragma unroll
    for (int dt = 0; dt < HD; dt += 32) {
        bf16x8 af[2], bq_[4];
#pragma unroll
        for (int jt = 0; jt < 2; ++jt)
            af[jt] = *(const bf16x8*)&Ks[(wave * 32 + jt * 16 + c) * 64 + dt + q * 8];
#pragma unroll
        for (int it = 0; it < 4; ++it)
            bq_[it] = *(const bf16x8*)&Qs[(it * 16 + c) * 64 + dt + q * 8];
#pragma unroll
        for (int jt = 0; jt < 2; ++jt)
#pragma unroll
            for (int it = 0; it < 4; ++it)
                acc[jt][it] = __builtin_amdgcn_mfma_f32_16x16x32_bf16(
                    af[jt], bq_[it], acc[jt][it], 0, 0, 0);
    }
    float rsum[4] = {0.f, 0.f, 0.f, 0.f};
#pragma unroll
    for (int jt = 0; jt < 2; ++jt)
#pragma unroll
        for (int it = 0; it < 4; ++it) {
            float e0 = __expf(acc[jt][it][0] * 0.125f);
            float e1 = __expf(acc[jt][it][1] * 0.125f);
            float e2 = __expf(acc[jt][it][2] * 0.125f);
            float e3 = __expf(acc[jt][it][3] * 0.125f);
            rsum[it] += (e0 + e1) + (e2 + e3);
            *(unsigned*)&Es[(it * 16 + c) * 144 + wave * 32 + jt * 16 + q * 4] =
                fp8_pack4(e0, e1, e2, e3);
        }
#pragma unroll
    for (int it = 0; it < 4; ++it) {
        rsum[it] += __shfl_xor(rsum[it], 16, 64);
        rsum[it] += __shfl_xor(rsum[it], 32, 64);
    }
    if (q == 0) {
#pragma unroll
        for (int it = 0; it < 4; ++it) red[wave][it * 16 + c] = rsum[it];
    }
    __syncthreads();
    {   // coalesced full-line E stores: 4 threads cover one 128-B row
        const int row = tid >> 2, off = (tid & 3) * 32;
        uint4 v0 = *(const uint4*)&Es[row * 144 + off];
        uint4 v1 = *(const uint4*)&Es[row * 144 + off + 16];
        unsigned char* dst = E + ((size_t)h * S_LEN + i0 + row) * S_LEN + j0 + off;
        *(uint4*)dst = v0;
        *(uint4*)(dst + 16) = v1;
    }
    if (tid < 64)
        rp[((size_t)h * 16 + blockIdx.x) * S_LEN + i0 + tid] =
            (red[0][tid] + red[1][tid]) + (red[2][tid] + red[3][tid]);
}

// ---------------------------------------------------------------------------
// Fused Sinkhorn pass, streaming (no E in LDS):
//   phase 1: a[i] = mu / (E·b)[i]  (rows direct global->VGPR, b in padded LDS)
//   phase 2: tp[h][chunk][j] = sum_i a[i]*E[i][j]  (re-read rows, L2-hot)
// grid (NCH=128, 12), block 256 (4 waves, 4 rows/wave).  LDS ~9 KB.
#define BPAD(j) ((j) + ((j) >> 4))              // +1 float pad per 16 -> conflict-free
__global__ __launch_bounds__(256) void sink_pass(
    const unsigned char* __restrict__ E, const float* __restrict__ bvec,
    const float* __restrict__ rp, float* __restrict__ aout,
    float* __restrict__ tpart, int use_rp) {
    __shared__ float lb[2048 + 128];            // padded b
    __shared__ float la[CH];
    const int h = blockIdx.y, chunk = blockIdx.x;
    const int tid = threadIdx.x, wave = tid >> 6, lane = tid & 63;
    const unsigned char* gbase = E + ((size_t)h * S_LEN + chunk * CH) * S_LEN;
    if (use_rp) {
        if (tid < CH) {
            float s = 0.f;
#pragma unroll
            for (int jt = 0; jt < 16; ++jt)
                s += rp[((size_t)h * 16 + jt) * S_LEN + chunk * CH + tid];
            la[tid] = MU / s;
        }
        __syncthreads();
    } else {
        {   // stage b (padded layout)
            const float* bg = bvec + (size_t)h * S_LEN;
#pragma unroll
            for (int p = 0; p < 8; ++p) {
                int j = p * 256 + tid;
                lb[BPAD(j)] = bg[j];
            }
        }
        __syncthreads();
        // phase 1: wave w -> rows w*4..w*4+3; lane covers j = lane*16 (+1024)
        const int jA = lane * 16, jB = 1024 + lane * 16;
        uint4 eA[4], eB[4];
#pragma unroll
        for (int rr = 0; rr < 4; ++rr) {
            const unsigned char* er = gbase + (size_t)(wave * 4 + rr) * S_LEN;
            eA[rr] = *(const uint4*)&er[jA];
            eB[rr] = *(const uint4*)&er[jB];
        }
        float bA[16], bB[16];
#pragma unroll
        for (int m = 0; m < 16; ++m) { bA[m] = lb[BPAD(jA + m)]; bB[m] = lb[BPAD(jB + m)]; }
#pragma unroll
        for (int rr = 0; rr < 4; ++rr) {
            float s = 0.f;
            unsigned wA[4] = {eA[rr].x, eA[rr].y, eA[rr].z, eA[rr].w};
            unsigned wB[4] = {eB[rr].x, eB[rr].y, eB[rr].z, eB[rr].w};
#pragma unroll
            for (int m = 0; m < 4; ++m) {
                f32x2 lo = fp8_dec_lo(wA[m]), hi = fp8_dec_hi(wA[m]);
                s += lo.x * bA[m*4] + lo.y * bA[m*4+1] + hi.x * bA[m*4+2] + hi.y * bA[m*4+3];
                lo = fp8_dec_lo(wB[m]); hi = fp8_dec_hi(wB[m]);
                s += lo.x * bB[m*4] + lo.y * bB[m*4+1] + hi.x * bB[m*4+2] + hi.y * bB[m*4+3];
            }
#pragma unroll
            for (int off = 32; off; off >>= 1) s += __shfl_xor(s, off, 64);
            if (lane == 0) la[wave * 4 + rr] = MU / s;
        }
        __syncthreads();
    }
    if (aout != nullptr && tid < CH)
        aout[(size_t)h * S_LEN + chunk * CH + tid] = la[tid];
    // phase 2: column partials; re-read rows from global (L2-hot), 8-batched
    {
        const int j0 = tid * 8;
        const unsigned char* eb = gbase + j0;
        float acc[8] = {};
#pragma unroll
        for (int g = 0; g < 2; ++g) {
            uint2 e[8];
#pragma unroll
            for (int r = 0; r < 8; ++r)
                e[r] = *(const uint2*)&eb[(size_t)(g * 8 + r) * S_LEN];
#pragma unroll
            for (int r = 0; r < 8; ++r) {
                float ar = la[g * 8 + r];
                f32x2 lo = fp8_dec_lo(e[r].x), hi = fp8_dec_hi(e[r].x);
                acc[0] += lo.x * ar; acc[1] += lo.y * ar; acc[2] += hi.x * ar; acc[3] += hi.y * ar;
                lo = fp8_dec_lo(e[r].y); hi = fp8_dec_hi(e[r].y);
                acc[4] += lo.x * ar; acc[5] += lo.y * ar; acc[6] += hi.x * ar; acc[7] += hi.y * ar;
            }
        }
        float* outp = tpart + ((size_t)h * NCH + chunk) * S_LEN + j0;
        float4 o0 = {acc[0], acc[1], acc[2], acc[3]};
        float4 o1 = {acc[4], acc[5], acc[6], acc[7]};
        *(float4*)&outp[0] = o0;
        *(float4*)&outp[4] = o1;
    }
}

// b[h][j] = mu / sum_chunk tp.  grid (NH*S/256), block 256
__global__ __launch_bounds__(256) void col_combine(
    const float* __restrict__ tpart, float* __restrict__ bout) {
    int g = blockIdx.x * 256 + threadIdx.x;
    int h = g >> 11, j = g & 2047;
    float s = 0.f;
#pragma unroll 8
    for (int c = 0; c < NCH; ++c) s += tpart[((size_t)h * NCH + c) * S_LEN + j];
    bout[g] = MU / s;
}

// ---------------------------------------------------------------------------
// Fused b3-combine + V scaling: b[j]=mu/sum tp, V't[h][d][j]=fp8(b[j]*V[j][d])
// grid (S/64 = 32, 12), block 256
__global__ __launch_bounds__(256) void col_combine_scale(
    const float* __restrict__ tpart, const unsigned short* __restrict__ Vb,
    unsigned char* __restrict__ Vt) {
    const int h = blockIdx.y, j0 = blockIdx.x * 64;
    __shared__ float lb[64];
    __shared__ unsigned char t[64][80];
    {
        int j = threadIdx.x >> 2, seg = threadIdx.x & 3;
        float s = 0.f;
#pragma unroll
        for (int cc = 0; cc < NCH / 4; ++cc)
            s += tpart[((size_t)h * NCH + seg * (NCH / 4) + cc) * S_LEN + j0 + j];
        s += __shfl_down(s, 2, 4);
        s += __shfl_down(s, 1, 4);
        if (seg == 0) lb[j] = MU / s;
    }
    __syncthreads();
    {
        const int r = threadIdx.x >> 2, dc = (threadIdx.x & 3) * 16;
        float bj = lb[r];
        const unsigned short* vrow = Vb + ((size_t)h * S_LEN + j0 + r) * HD + dc;
#pragma unroll
        for (int k = 0; k < 16; ++k) t[dc + k][r] = fp8_enc(bf2f(vrow[k]) * bj);
    }
    __syncthreads();
    const int d = threadIdx.x >> 2, jc = (threadIdx.x & 3) * 16;
    unsigned char* out = Vt + ((size_t)h * HD + d) * S_LEN + j0 + jc;
    *(uint4*)out = *(const uint4*)&t[d][jc];
}

// ---------------------------------------------------------------------------
// ctx[i][h*64+d] = a_i*n * sum_j E[h][i][j]*V't[h][d][j].  fp8 MFMA.
// 32 i-rows/block (2 i-tiles/wave, V-frags shared), 4-way j-split,
// 2-stage pipeline with 12 loads in flight.  grid (64, 12), block 256.
__global__ __launch_bounds__(256) void attn_av(
    const unsigned char* __restrict__ E, const float* __restrict__ a,
    const unsigned char* __restrict__ Vt, unsigned short* __restrict__ ctxb) {
    const int h = blockIdx.y;
    const int wave = threadIdx.x >> 6, lane = threadIdx.x & 63;
    const int q = lane >> 4, c = lane & 15;
    const int i0 = blockIdx.x * 32;
    const unsigned char* e0 = E + (size_t)h * S_LEN * S_LEN + (size_t)(i0 + c) * S_LEN;
    const unsigned char* e1 = e0 + (size_t)16 * S_LEN;
    const unsigned char* Vh = Vt + (size_t)h * HD * S_LEN;
    const int jb = wave * 512;
    f32x4 acc[2][4] = {};
    i64_t eN[2][2], vN[4][2];
#pragma unroll
    for (int kk = 0; kk < 2; ++kk) {
        eN[0][kk] = *(const i64_t*)&e0[jb + kk * 32 + q * 8];
        eN[1][kk] = *(const i64_t*)&e1[jb + kk * 32 + q * 8];
#pragma unroll
        for (int s = 0; s < 4; ++s)
            vN[s][kk] = *(const i64_t*)&Vh[(size_t)(s * 16 + c) * S_LEN + jb + kk * 32 + q * 8];
    }
    for (int jt = jb; jt < jb + 512; jt += 64) {
        i64_t eC[2][2], vC[4][2];
#pragma unroll
        for (int kk = 0; kk < 2; ++kk) {
            eC[0][kk] = eN[0][kk]; eC[1][kk] = eN[1][kk];
#pragma unroll
            for (int s = 0; s < 4; ++s) vC[s][kk] = vN[s][kk];
        }
        if (jt + 64 < jb + 512) {
            const int jn = jt + 64;
#pragma unroll
            for (int kk = 0; kk < 2; ++kk) {
                eN[0][kk] = *(const i64_t*)&e0[jn + kk * 32 + q * 8];
                eN[1][kk] = *(const i64_t*)&e1[jn + kk * 32 + q * 8];
#pragma unroll
                for (int s = 0; s < 4; ++s)
                    vN[s][kk] = *(const i64_t*)&Vh[(size_t)(s * 16 + c) * S_LEN + jn + kk * 32 + q * 8];
            }
        }
#pragma unroll
        for (int kk = 0; kk < 2; ++kk)
#pragma unroll
            for (int it = 0; it < 2; ++it)
#pragma unroll
                for (int s = 0; s < 4; ++s)
                    acc[it][s] = __builtin_amdgcn_mfma_f32_16x16x32_fp8_fp8(
                        eC[it][kk], vC[s][kk], acc[it][s], 0, 0, 0);
    }
    __shared__ float lred[3][2][16][64];        // 24 KB
    if (wave != 0) {
#pragma unroll
        for (int it = 0; it < 2; ++it)
#pragma unroll
            for (int s = 0; s < 4; ++s)
#pragma unroll
                for (int r = 0; r < 4; ++r)
                    lred[wave - 1][it][s * 4 + r][lane] = acc[it][s][r];
    }
    __syncthreads();
    if (wave == 0) {
#pragma unroll
        for (int it = 0; it < 2; ++it) {
            float ais[4];
#pragma unroll
            for (int r = 0; r < 4; ++r)
                ais[r] = a[(size_t)h * S_LEN + i0 + it * 16 + q * 4 + r] * 2048.f;
#pragma unroll
            for (int s = 0; s < 4; ++s)
#pragma unroll
                for (int r = 0; r < 4; ++r) {
                    float v = acc[it][s][r] +
                              ((lred[0][it][s * 4 + r][lane] + lred[1][it][s * 4 + r][lane]) +
                               lred[2][it][s * 4 + r][lane]);
                    ctxb[(size_t)(i0 + it * 16 + q * 4 + r) * E_DIM + h * 64 + s * 16 + c] =
                        f2bf(v * ais[r]);
                }
        }
    }
}

// ---------------------------------------------------------------------------
// Y = ctx @ Wo + bo + X (fp32), gll staging, tile 128x64.  grid (12, 16), 256
__global__ __launch_bounds__(256) void out_gemm(
    const unsigned short* __restrict__ ctxb, const unsigned short* __restrict__ Wt,
    const float* __restrict__ bo, const float* __restrict__ X, float* __restrict__ Y) {
    __shared__ unsigned short As[128 * 64];
    __shared__ unsigned short Bs[64 * 64];
    __shared__ float Csf[64 * 64];
    const int n0 = blockIdx.x * 64;
    const int row0 = blockIdx.y * 128;
    const int tid = threadIdx.x;
    const int wave = tid >> 6, lane = tid & 63;
    const int wm = wave & 1, wn = wave >> 1;
    const int q = lane >> 4, c = lane & 15;
    const int lrow = lane >> 3, lk8 = (lane & 7) * 8;
    const unsigned short* Wo3 = Wt + (size_t)3 * E_DIM * E_DIM + (size_t)n0 * E_DIM;
    f32x4 acc[4][2] = {};
    for (int kt = 0; kt < E_DIM; kt += 64) {
        __syncthreads();
#if HAS_GLL
#pragma unroll
        for (int p = 0; p < 4; ++p)
            gll16(&ctxb[(size_t)(row0 + p * 32 + wave * 8 + lrow) * E_DIM + kt + lk8],
                  &As[(p * 32 + wave * 8) * 64]);
#pragma unroll
        for (int p = 0; p < 2; ++p)
            gll16(&Wo3[(size_t)(p * 32 + wave * 8 + lrow) * E_DIM + kt + lk8],
                  &Bs[(p * 32 + wave * 8) * 64]);
#else
        {
            uint4 ta[4], tb[2];
#pragma unroll
            for (int p = 0; p < 4; ++p)
                ta[p] = *(const uint4*)&ctxb[(size_t)(row0 + p * 32 + wave * 8 + lrow) * E_DIM + kt + lk8];
#pragma unroll
            for (int p = 0; p < 2; ++p)
                tb[p] = *(const uint4*)&Wo3[(size_t)(p * 32 + wave * 8 + lrow) * E_DIM + kt + lk8];
#pragma unroll
            for (int p = 0; p < 4; ++p) *(uint4*)&As[(p * 32 + wave * 8 + lrow) * 64 + lk8] = ta[p];
#pragma unroll
            for (int p = 0; p < 2; ++p) *(uint4*)&Bs[(p * 32 + wave * 8 + lrow) * 64 + lk8] = tb[p];
        }
#endif
        __syncthreads();
#pragma unroll
        for (int ks = 0; ks < 2; ++ks) {
            bf16x8 af[4], bfr[2];
#pragma unroll
            for (int mi = 0; mi < 4; ++mi)
                af[mi] = *(const bf16x8*)&As[(wm * 64 + mi * 16 + c) * 64 + ks * 32 + q * 8];
#pragma unroll
            for (int ni = 0; ni < 2; ++ni)
                bfr[ni] = *(const bf16x8*)&Bs[(wn * 32 + ni * 16 + c) * 64 + ks * 32 + q * 8];
#pragma unroll
            for (int mi = 0; mi < 4; ++mi)
#pragma unroll
                for (int ni = 0; ni < 2; ++ni)
                    acc[mi][ni] = __builtin_amdgcn_mfma_f32_16x16x32_bf16(
                        af[mi], bfr[ni], acc[mi][ni], 0, 0, 0);
        }
    }
#pragma unroll
    for (int pp = 0; pp < 2; ++pp) {
        __syncthreads();
        if (wm == pp) {
#pragma unroll
            for (int mi = 0; mi < 4; ++mi)
#pragma unroll
                for (int ni = 0; ni < 2; ++ni)
#pragma unroll
                    for (int r = 0; r < 4; ++r)
                        Csf[(mi * 16 + q * 4 + r) * 64 + wn * 32 + ni * 16 + c] = acc[mi][ni][r];
        }
        __syncthreads();
#pragma unroll
        for (int sp = 0; sp < 4; ++sp) {
            int row = sp * 16 + (tid >> 4);
            int col = (tid & 15) * 4;
            int grow = row0 + pp * 64 + row;
            float4 v = *(const float4*)&Csf[row * 64 + col];
            const float4 xr = *(const float4*)&X[(size_t)grow * E_DIM + n0 + col];
            const float4 bb = *(const float4*)&bo[n0 + col];
            float4 o = {v.x + bb.x + xr.x, v.y + bb.y + xr.y,
                        v.z + bb.z + xr.z, v.w + bb.w + xr.w};
            *(float4*)&Y[(size_t)grow * E_DIM + n0 + col] = o;
        }
    }
}

// ---------------------------------------------------------------------------
// LayerNorm per row.  grid (S), block 256
__global__ __launch_bounds__(256) void layernorm(
    const float* __restrict__ Y, const float* __restrict__ g,
    const float* __restrict__ b, float* __restrict__ out) {
    __shared__ float red[4];
    const int srow = blockIdx.x;
    const float* yr = Y + (size_t)srow * E_DIM;
    const int t = threadIdx.x;
    float xs[3];
    float sum = 0.f;
#pragma unroll
    for (int r = 0; r < 3; ++r) { xs[r] = yr[t + r * 256]; sum += xs[r]; }
#pragma unroll
    for (int off = 32; off; off >>= 1) sum += __shfl_down(sum, off, 64);
    if ((t & 63) == 0) red[t >> 6] = sum;
    __syncthreads();
    sum = red[0] + red[1] + red[2] + red[3];
    const float mu = sum * (1.f / 768.f);
    float vs = 0.f;
#pragma unroll
    for (int r = 0; r < 3; ++r) { float d = xs[r] - mu; vs += d * d; }
    __syncthreads();
#pragma unroll
    for (int off = 32; off; off >>= 1) vs += __shfl_down(vs, off, 64);
    if ((t & 63) == 0) red[t >> 6] = vs;
    __syncthreads();
    vs = red[0] + red[1] + red[2] + red[3];
    const float inv = rsqrtf(vs * (1.f / 768.f) + LN_EPS);
#pragma unroll
    for (int r = 0; r < 3; ++r) {
        int c = t + r * 256;
        out[(size_t)srow * E_DIM + c] = g[c] * (xs[r] - mu) * inv + b[c];
    }
}

// ---------------------------------------------------------------------------
extern "C" void kernel_launch(void* const* d_in, const int* in_sizes, int n_in,
                              void* d_out, int out_size, void* d_ws, size_t ws_size,
                              hipStream_t stream) {
    const float* X    = (const float*)d_in[0];
    const float* Wq   = (const float*)d_in[1];
    const float* bq   = (const float*)d_in[2];
    const float* Wk   = (const float*)d_in[3];
    const float* bk   = (const float*)d_in[4];
    const float* Wv   = (const float*)d_in[5];
    const float* bv   = (const float*)d_in[6];
    const float* Wo   = (const float*)d_in[7];
    const float* bo   = (const float*)d_in[8];
    const float* ln_g = (const float*)d_in[9];
    const float* ln_b = (const float*)d_in[10];
    float* out = (float*)d_out;

    char* p = (char*)d_ws;
    auto alloc = [&](size_t bytes) { char* r = p; p += (bytes + 255) & ~(size_t)255; return r; };
    unsigned short* Xb   = (unsigned short*)alloc((size_t)S_LEN * E_DIM * 2);
    unsigned short* Wt   = (unsigned short*)alloc((size_t)4 * E_DIM * E_DIM * 2);
    unsigned short* Qb   = (unsigned short*)alloc((size_t)NH * S_LEN * HD * 2);
    unsigned short* Kb   = (unsigned short*)alloc((size_t)NH * S_LEN * HD * 2);
    unsigned short* Vb   = (unsigned short*)alloc((size_t)NH * S_LEN * HD * 2);
    unsigned char*  E    = (unsigned char*)alloc((size_t)NH * S_LEN * S_LEN);   // 48 MB fp8
    float*          rp   = (float*)alloc((size_t)NH * 16 * S_LEN * 4);
    float*          av   = (float*)alloc((size_t)NH * S_LEN * 4);
    float*          bv_  = (float*)alloc((size_t)NH * S_LEN * 4);
    float*          tp   = (float*)alloc((size_t)NH * NCH * S_LEN * 4);         // 12 MB
    unsigned char*  Vt   = (unsigned char*)alloc((size_t)NH * HD * S_LEN);
    unsigned short* ctxb = (unsigned short*)alloc((size_t)S_LEN * E_DIM * 2);
    float*          Y    = (float*)alloc((size_t)S_LEN * E_DIM * 4);

    quant_all<<<1536 + 4 * 576, 256, 0, stream>>>(X, Xb, Wq, Wk, Wv, Wo, Wt);
    qkv_gemm<<<dim3(36, 16), 256, 0, stream>>>(Xb, Wt, bq, bk, bv, Qb, Kb, Vb);
    score_exp<<<dim3(16, 32, NH), 256, 0, stream>>>(Qb, Kb, E, rp);

    // Sinkhorn: 3 fused streaming passes
    sink_pass<<<dim3(NCH, NH), 256, 0, stream>>>(E, bv_, rp, nullptr, tp, 1);    // a1->tp
    col_combine<<<NH * S_LEN / 256, 256, 0, stream>>>(tp, bv_);                  // b1
    sink_pass<<<dim3(NCH, NH), 256, 0, stream>>>(E, bv_, rp, nullptr, tp, 0);    // a2->tp
    col_combine<<<NH * S_LEN / 256, 256, 0, stream>>>(tp, bv_);                  // b2
    sink_pass<<<dim3(NCH, NH), 256, 0, stream>>>(E, bv_, rp, av, tp, 0);         // a3->tp (+a3 out)
    col_combine_scale<<<dim3(S_LEN / 64, NH), 256, 0, stream>>>(tp, Vb, Vt);     // b3 + scale V

    attn_av<<<dim3(S_LEN / 32, NH), 256, 0, stream>>>(E, av, Vt, ctxb);
    out_gemm<<<dim3(12, 16), 256, 0, stream>>>(ctxb, Wt, bo, X, Y);
    layernorm<<<S_LEN, 256, 0, stream>>>(Y, ln_g, ln_b, out);
}

// Round 14
// 229.723 us; speedup vs baseline: 4.5597x; 1.0412x over previous
//
#include <hip/hip_runtime.h>
#include <math.h>

#define S_LEN 2048
#define E_DIM 768
#define NH    12
#define HD    64
#define MU    (1.0f/2048.0f)
#define LN_EPS 1e-12f
#define CH    32            // sink_pass chunk rows
#define NCH   (S_LEN/CH)    // 64 chunks

typedef __attribute__((ext_vector_type(8))) short bf16x8;   // 8 bf16 (4 VGPRs)
typedef __attribute__((ext_vector_type(4))) float f32x4;    // MFMA accumulator
typedef __attribute__((ext_vector_type(2))) float f32x2;
typedef long i64_t;                                          // 8 fp8 (2 VGPRs)

__device__ __forceinline__ unsigned short f2bf(float f) {   // RNE fp32->bf16
    unsigned u = __float_as_uint(f);
    u += 0x7fff + ((u >> 16) & 1);
    return (unsigned short)(u >> 16);
}
__device__ __forceinline__ float bf2f(unsigned short h) {
    return __uint_as_float(((unsigned)h) << 16);
}

// ---- fp8 e4m3 (OCP) helpers ----
__device__ __forceinline__ unsigned char fp8_enc(float f) {
#if __has_builtin(__builtin_amdgcn_cvt_pk_fp8_f32)
    return (unsigned char)(__builtin_amdgcn_cvt_pk_fp8_f32(f, f, 0, false) & 0xFF);
#else
    float m = fminf(fabsf(f), 448.f) * 0x1p-120f;
    unsigned b = __float_as_uint(m);
    unsigned s = (__float_as_uint(f) >> 24) & 0x80u;
    b += 0x7FFFFu + ((b >> 20) & 1u);
    return (unsigned char)(s | ((b >> 20) & 0x7Fu));
#endif
}
// pack 4 floats -> 4 fp8 bytes in one dword
__device__ __forceinline__ unsigned fp8_pack4(float e0, float e1, float e2, float e3) {
#if __has_builtin(__builtin_amdgcn_cvt_pk_fp8_f32)
    unsigned u = __builtin_amdgcn_cvt_pk_fp8_f32(e0, e1, 0, false);
    u = __builtin_amdgcn_cvt_pk_fp8_f32(e2, e3, u, true);
    return u;
#else
    return (unsigned)fp8_enc(e0) | ((unsigned)fp8_enc(e1) << 8) |
           ((unsigned)fp8_enc(e2) << 16) | ((unsigned)fp8_enc(e3) << 24);
#endif
}
__device__ __forceinline__ float fp8_dec1(unsigned char u) {
    unsigned bits = ((u & 0x80u) << 24) | ((u & 0x7Fu) << 20);
    return __uint_as_float(bits) * 0x1p+120f;
}
__device__ __forceinline__ f32x2 fp8_dec_lo(unsigned v) {
#if __has_builtin(__builtin_amdgcn_cvt_pk_f32_fp8)
    return __builtin_amdgcn_cvt_pk_f32_fp8(v, false);
#else
    f32x2 r; r.x = fp8_dec1(v & 0xFF); r.y = fp8_dec1((v >> 8) & 0xFF); return r;
#endif
}
__device__ __forceinline__ f32x2 fp8_dec_hi(unsigned v) {
#if __has_builtin(__builtin_amdgcn_cvt_pk_f32_fp8)
    return __builtin_amdgcn_cvt_pk_f32_fp8(v, true);
#else
    f32x2 r; r.x = fp8_dec1((v >> 16) & 0xFF); r.y = fp8_dec1(v >> 24); return r;
#endif
}

// ---- async global->LDS, 16 B per lane (dest = wave-uniform base + lane*16) ----
#if defined(__has_builtin)
#if __has_builtin(__builtin_amdgcn_global_load_lds)
#define HAS_GLL 1
#endif
#endif
#if HAS_GLL
__device__ __forceinline__ void gll16(const void* g, void* l) {
    __builtin_amdgcn_global_load_lds(
        (__attribute__((address_space(1))) void*)(void*)g,
        (__attribute__((address_space(3))) void*)l, 16, 0, 0);
}
#endif

// ---------------------------------------------------------------------------
// Merged preprocessing: X fp32->bf16 (blocks 0..1535) + 4x W fp32->bf16^T
// (blocks 1536..3839: 4 matrices x 576 32x32-tiles).  block 256.
__global__ __launch_bounds__(256) void quant_all(
    const float* __restrict__ X, unsigned short* __restrict__ Xb,
    const float* __restrict__ W0, const float* __restrict__ W1,
    const float* __restrict__ W2, const float* __restrict__ W3,
    unsigned short* __restrict__ Wt) {
    const int b = blockIdx.x;
    if (b < 1536) {                 // X quant: one float4 per thread
        int i = b * 256 + threadIdx.x;
        const float4 v = ((const float4*)X)[i];
        ushort4 o = { f2bf(v.x), f2bf(v.y), f2bf(v.z), f2bf(v.w) };
        ((ushort4*)Xb)[i] = o;
        return;
    }
    const int wb = b - 1536;
    const int z = wb / 576, t = wb % 576;
    const float* W = (z == 0) ? W0 : (z == 1) ? W1 : (z == 2) ? W2 : W3;
    __shared__ unsigned short tsm[32][33];
    const int n0 = (t % 24) * 32, k0 = (t / 24) * 32;
    const int c = threadIdx.x & 31, r8 = threadIdx.x >> 5;
#pragma unroll
    for (int rr = 0; rr < 32; rr += 8) {
        int k = k0 + r8 + rr;
        tsm[c][r8 + rr] = f2bf(W[(size_t)k * E_DIM + n0 + c]);
    }
    __syncthreads();
    unsigned short* out = Wt + (size_t)z * E_DIM * E_DIM;
#pragma unroll
    for (int rr = 0; rr < 32; rr += 8) {
        int n = n0 + r8 + rr;
        out[(size_t)n * E_DIM + k0 + c] = tsm[r8 + rr][c];
    }
}

// ---------------------------------------------------------------------------
// Fused QKV GEMM, global_load_lds staging, tile 128x64, BK=64.
// grid (36 n-tiles, 16 row-tiles), block 256.  All outputs bf16 [h][s][64].
__global__ __launch_bounds__(256) void qkv_gemm(
    const unsigned short* __restrict__ Xb, const unsigned short* __restrict__ Wt,
    const float* __restrict__ bq, const float* __restrict__ bk, const float* __restrict__ bv,
    unsigned short* __restrict__ Qb, unsigned short* __restrict__ Kb,
    unsigned short* __restrict__ Vb) {
    __shared__ unsigned short As[128 * 64];     // unpadded: required by gll
    __shared__ unsigned short Bs[64 * 64];
    const int n0 = blockIdx.x * 64;
    const int row0 = blockIdx.y * 128;
    const int tid = threadIdx.x;
    const int wave = tid >> 6, lane = tid & 63;
    const int wm = wave & 1, wn = wave >> 1;
    const int q = lane >> 4, c = lane & 15;
    const int lrow = lane >> 3, lk8 = (lane & 7) * 8;
    const unsigned short* Wb = Wt + (size_t)n0 * E_DIM;
    f32x4 acc[4][2] = {};
    for (int kt = 0; kt < E_DIM; kt += 64) {
        __syncthreads();
#if HAS_GLL
#pragma unroll
        for (int p = 0; p < 4; ++p)
            gll16(&Xb[(size_t)(row0 + p * 32 + wave * 8 + lrow) * E_DIM + kt + lk8],
                  &As[(p * 32 + wave * 8) * 64]);
#pragma unroll
        for (int p = 0; p < 2; ++p)
            gll16(&Wb[(size_t)(p * 32 + wave * 8 + lrow) * E_DIM + kt + lk8],
                  &Bs[(p * 32 + wave * 8) * 64]);
#else
        {
            uint4 ta[4], tb[2];
#pragma unroll
            for (int p = 0; p < 4; ++p)
                ta[p] = *(const uint4*)&Xb[(size_t)(row0 + p * 32 + wave * 8 + lrow) * E_DIM + kt + lk8];
#pragma unroll
            for (int p = 0; p < 2; ++p)
                tb[p] = *(const uint4*)&Wb[(size_t)(p * 32 + wave * 8 + lrow) * E_DIM + kt + lk8];
#pragma unroll
            for (int p = 0; p < 4; ++p) *(uint4*)&As[(p * 32 + wave * 8 + lrow) * 64 + lk8] = ta[p];
#pragma unroll
            for (int p = 0; p < 2; ++p) *(uint4*)&Bs[(p * 32 + wave * 8 + lrow) * 64 + lk8] = tb[p];
        }
#endif
        __syncthreads();
#pragma unroll
        for (int ks = 0; ks < 2; ++ks) {
            bf16x8 af[4], bfr[2];
#pragma unroll
            for (int mi = 0; mi < 4; ++mi)
                af[mi] = *(const bf16x8*)&As[(wm * 64 + mi * 16 + c) * 64 + ks * 32 + q * 8];
#pragma unroll
            for (int ni = 0; ni < 2; ++ni)
                bfr[ni] = *(const bf16x8*)&Bs[(wn * 32 + ni * 16 + c) * 64 + ks * 32 + q * 8];
#pragma unroll
            for (int mi = 0; mi < 4; ++mi)
#pragma unroll
                for (int ni = 0; ni < 2; ++ni)
                    acc[mi][ni] = __builtin_amdgcn_mfma_f32_16x16x32_bf16(
                        af[mi], bfr[ni], acc[mi][ni], 0, 0, 0);
        }
    }
    const int z = n0 / E_DIM;
    const int h = (n0 % E_DIM) >> 6;
    const float* bias = (z == 0) ? bq : (z == 1) ? bk : bv;
    unsigned short* outp = (z == 0) ? Qb : (z == 1) ? Kb : Vb;
    __syncthreads();
    unsigned short* Cs = As;                    // reuse 16 KB for repack
#pragma unroll
    for (int ni = 0; ni < 2; ++ni) {
        const int col = wn * 32 + ni * 16 + c;
        const float bb = bias[h * 64 + col];
#pragma unroll
        for (int mi = 0; mi < 4; ++mi)
#pragma unroll
            for (int r = 0; r < 4; ++r)
                Cs[(wm * 64 + mi * 16 + q * 4 + r) * 64 + col] = f2bf(acc[mi][ni][r] + bb);
    }
    __syncthreads();
#pragma unroll
    for (int pp = 0; pp < 4; ++pp) {
        int row = pp * 32 + (tid >> 3);
        *(uint4*)&outp[((size_t)h * S_LEN + row0 + row) * HD + (tid & 7) * 8] =
            *(const uint4*)&Cs[row * 64 + (tid & 7) * 8];
    }
}

// ---------------------------------------------------------------------------
// E = exp(QK^T/8) -> fp8.  SWAPPED operands (A=K, B=Q): D[m=j][n=i].
// grid (16 j-tiles(128), 32 i-tiles(64), 12 h), block 256.
__global__ __launch_bounds__(256) void score_exp(
    const unsigned short* __restrict__ Qb, const unsigned short* __restrict__ Kb,
    unsigned char* __restrict__ E, float* __restrict__ rp) {
    const int h = blockIdx.z;
    const int i0 = blockIdx.y * 64, j0 = blockIdx.x * 128;
    const int tid = threadIdx.x;
    const int wave = tid >> 6, lane = tid & 63;
    const int q = lane >> 4, c = lane & 15;
    __shared__ unsigned short Qs[64 * 64];
    __shared__ unsigned short Ks[128 * 64];
    __shared__ unsigned char  Es[64 * 144];     // row stride 144 B (pad: 2-way max)
    __shared__ float red[4][64];
    const unsigned short* Qh = Qb + (size_t)h * S_LEN * HD;
    const unsigned short* Kh = Kb + (size_t)h * S_LEN * HD;
    const int lrow = lane >> 3, lk8 = (lane & 7) * 8;
#if HAS_GLL
#pragma unroll
    for (int p = 0; p < 2; ++p)
        gll16(&Qh[(size_t)(i0 + p * 32 + wave * 8 + lrow) * HD + lk8],
              &Qs[(p * 32 + wave * 8) * 64]);
#pragma unroll
    for (int p = 0; p < 4; ++p)
        gll16(&Kh[(size_t)(j0 + p * 32 + wave * 8 + lrow) * HD + lk8],
              &Ks[(p * 32 + wave * 8) * 64]);
#else
    {
        uint4 tq[2], tk[4];
#pragma unroll
        for (int p = 0; p < 2; ++p)
            tq[p] = *(const uint4*)&Qh[(size_t)(i0 + p * 32 + wave * 8 + lrow) * HD + lk8];
#pragma unroll
        for (int p = 0; p < 4; ++p)
            tk[p] = *(const uint4*)&Kh[(size_t)(j0 + p * 32 + wave * 8 + lrow) * HD + lk8];
#pragma unroll
        for (int p = 0; p < 2; ++p) *(uint4*)&Qs[(p * 32 + wave * 8 + lrow) * 64 + lk8] = tq[p];
#pragma unroll
        for (int p = 0; p < 4; ++p) *(uint4*)&Ks[(p * 32 + wave * 8 + lrow) * 64 + lk8] = tk[p];
    }
#endif
    __syncthreads();
    f32x4 acc[2][4] = {};                       // [jt][it]; wave covers j = wave*32 + jt*16
#pragma unroll
    for (int dt = 0; dt < HD; dt += 32) {
        bf16x8 af[2], bq_[4];
#pragma unroll
        for (int jt = 0; jt < 2; ++jt)
            af[jt] = *(const bf16x8*)&Ks[(wave * 32 + jt * 16 + c) * 64 + dt + q * 8];
#pragma unroll
        for (int it = 0; it < 4; ++it)
            bq_[it] = *(const bf16x8*)&Qs[(it * 16 + c) * 64 + dt + q * 8];
#pragma unroll
        for (int jt = 0; jt < 2; ++jt)
#pragma unroll
            for (int it = 0; it < 4; ++it)
                acc[jt][it] = __builtin_amdgcn_mfma_f32_16x16x32_bf16(
                    af[jt], bq_[it], acc[jt][it], 0, 0, 0);
    }
    float rsum[4] = {0.f, 0.f, 0.f, 0.f};
#pragma unroll
    for (int jt = 0; jt < 2; ++jt)
#pragma unroll
        for (int it = 0; it < 4; ++it) {
            float e0 = __expf(acc[jt][it][0] * 0.125f);
            float e1 = __expf(acc[jt][it][1] * 0.125f);
            float e2 = __expf(acc[jt][it][2] * 0.125f);
            float e3 = __expf(acc[jt][it][3] * 0.125f);
            rsum[it] += (e0 + e1) + (e2 + e3);
            *(unsigned*)&Es[(it * 16 + c) * 144 + wave * 32 + jt * 16 + q * 4] =
                fp8_pack4(e0, e1, e2, e3);
        }
#pragma unroll
    for (int it = 0; it < 4; ++it) {
        rsum[it] += __shfl_xor(rsum[it], 16, 64);
        rsum[it] += __shfl_xor(rsum[it], 32, 64);
    }
    if (q == 0) {
#pragma unroll
        for (int it = 0; it < 4; ++it) red[wave][it * 16 + c] = rsum[it];
    }
    __syncthreads();
    {   // coalesced full-line E stores: 4 threads cover one 128-B row
        const int row = tid >> 2, off = (tid & 3) * 32;
        uint4 v0 = *(const uint4*)&Es[row * 144 + off];
        uint4 v1 = *(const uint4*)&Es[row * 144 + off + 16];
        unsigned char* dst = E + ((size_t)h * S_LEN + i0 + row) * S_LEN + j0 + off;
        *(uint4*)dst = v0;
        *(uint4*)(dst + 16) = v1;
    }
    if (tid < 64)
        rp[((size_t)h * 16 + blockIdx.x) * S_LEN + i0 + tid] =
            (red[0][tid] + red[1][tid]) + (red[2][tid] + red[3][tid]);
}

// ---------------------------------------------------------------------------
// Fused Sinkhorn pass, streaming, CH=32 rows/chunk:
//   phase 1: a[i] = mu / (E·b)[i]  (rows direct global->VGPR, b in padded LDS)
//   phase 2: tp[h][chunk][j] = sum_i a[i]*E[i][j]  (re-read rows, L2-hot)
// grid (NCH=64, 12), block 256 (4 waves, 8 rows/wave).  LDS ~9 KB.
#define BPAD(j) ((j) + ((j) >> 4))              // +1 float pad per 16 -> conflict-free
__global__ __launch_bounds__(256) void sink_pass(
    const unsigned char* __restrict__ E, const float* __restrict__ bvec,
    const float* __restrict__ rp, float* __restrict__ aout,
    float* __restrict__ tpart, int use_rp) {
    __shared__ float lb[2048 + 128];            // padded b
    __shared__ float la[CH];
    const int h = blockIdx.y, chunk = blockIdx.x;
    const int tid = threadIdx.x, wave = tid >> 6, lane = tid & 63;
    const unsigned char* gbase = E + ((size_t)h * S_LEN + chunk * CH) * S_LEN;
    if (use_rp) {
        if (tid < CH) {
            float s = 0.f;
#pragma unroll
            for (int jt = 0; jt < 16; ++jt)
                s += rp[((size_t)h * 16 + jt) * S_LEN + chunk * CH + tid];
            la[tid] = MU / s;
        }
        __syncthreads();
    } else {
        {   // stage b (padded layout)
            const float* bg = bvec + (size_t)h * S_LEN;
#pragma unroll
            for (int p = 0; p < 8; ++p) {
                int j = p * 256 + tid;
                lb[BPAD(j)] = bg[j];
            }
        }
        __syncthreads();
        // phase 1: wave w -> rows w*8..w*8+7; lane covers j = lane*16 (+1024)
        const int jA = lane * 16, jB = 1024 + lane * 16;
        float bA[16], bB[16];
#pragma unroll
        for (int m = 0; m < 16; ++m) { bA[m] = lb[BPAD(jA + m)]; bB[m] = lb[BPAD(jB + m)]; }
#pragma unroll
        for (int rg = 0; rg < 2; ++rg) {        // 2 groups of 4 rows
            uint4 eA[4], eB[4];
#pragma unroll
            for (int rr = 0; rr < 4; ++rr) {
                const unsigned char* er = gbase + (size_t)(wave * 8 + rg * 4 + rr) * S_LEN;
                eA[rr] = *(const uint4*)&er[jA];
                eB[rr] = *(const uint4*)&er[jB];
            }
#pragma unroll
            for (int rr = 0; rr < 4; ++rr) {
                float s = 0.f;
                unsigned wA[4] = {eA[rr].x, eA[rr].y, eA[rr].z, eA[rr].w};
                unsigned wB[4] = {eB[rr].x, eB[rr].y, eB[rr].z, eB[rr].w};
#pragma unroll
                for (int m = 0; m < 4; ++m) {
                    f32x2 lo = fp8_dec_lo(wA[m]), hi = fp8_dec_hi(wA[m]);
                    s += lo.x * bA[m*4] + lo.y * bA[m*4+1] + hi.x * bA[m*4+2] + hi.y * bA[m*4+3];
                    lo = fp8_dec_lo(wB[m]); hi = fp8_dec_hi(wB[m]);
                    s += lo.x * bB[m*4] + lo.y * bB[m*4+1] + hi.x * bB[m*4+2] + hi.y * bB[m*4+3];
                }
#pragma unroll
                for (int off = 32; off; off >>= 1) s += __shfl_xor(s, off, 64);
                if (lane == 0) la[wave * 8 + rg * 4 + rr] = MU / s;
            }
        }
        __syncthreads();
    }
    if (aout != nullptr && tid < CH)
        aout[(size_t)h * S_LEN + chunk * CH + tid] = la[tid];
    // phase 2: column partials; re-read rows from global (L2-hot), 8-batched
    {
        const int j0 = tid * 8;
        const unsigned char* eb = gbase + j0;
        float acc[8] = {};
#pragma unroll
        for (int g = 0; g < 4; ++g) {
            uint2 e[8];
#pragma unroll
            for (int r = 0; r < 8; ++r)
                e[r] = *(const uint2*)&eb[(size_t)(g * 8 + r) * S_LEN];
#pragma unroll
            for (int r = 0; r < 8; ++r) {
                float ar = la[g * 8 + r];
                f32x2 lo = fp8_dec_lo(e[r].x), hi = fp8_dec_hi(e[r].x);
                acc[0] += lo.x * ar; acc[1] += lo.y * ar; acc[2] += hi.x * ar; acc[3] += hi.y * ar;
                lo = fp8_dec_lo(e[r].y); hi = fp8_dec_hi(e[r].y);
                acc[4] += lo.x * ar; acc[5] += lo.y * ar; acc[6] += hi.x * ar; acc[7] += hi.y * ar;
            }
        }
        float* outp = tpart + ((size_t)h * NCH + chunk) * S_LEN + j0;
        float4 o0 = {acc[0], acc[1], acc[2], acc[3]};
        float4 o1 = {acc[4], acc[5], acc[6], acc[7]};
        *(float4*)&outp[0] = o0;
        *(float4*)&outp[4] = o1;
    }
}

// b[h][j] = mu / sum_chunk tp.  grid (NH*S/256), block 256
__global__ __launch_bounds__(256) void col_combine(
    const float* __restrict__ tpart, float* __restrict__ bout) {
    int g = blockIdx.x * 256 + threadIdx.x;
    int h = g >> 11, j = g & 2047;
    float s = 0.f;
#pragma unroll 8
    for (int c = 0; c < NCH; ++c) s += tpart[((size_t)h * NCH + c) * S_LEN + j];
    bout[g] = MU / s;
}

// ---------------------------------------------------------------------------
// Fused b3-combine + V scaling: b[j]=mu/sum tp, V't[h][d][j]=fp8(b[j]*V[j][d])
// grid (S/64 = 32, 12), block 256
__global__ __launch_bounds__(256) void col_combine_scale(
    const float* __restrict__ tpart, const unsigned short* __restrict__ Vb,
    unsigned char* __restrict__ Vt) {
    const int h = blockIdx.y, j0 = blockIdx.x * 64;
    __shared__ float lb[64];
    __shared__ unsigned char t[64][80];
    {
        int j = threadIdx.x >> 2, seg = threadIdx.x & 3;
        float s = 0.f;
#pragma unroll
        for (int cc = 0; cc < NCH / 4; ++cc)
            s += tpart[((size_t)h * NCH + seg * (NCH / 4) + cc) * S_LEN + j0 + j];
        s += __shfl_down(s, 2, 4);
        s += __shfl_down(s, 1, 4);
        if (seg == 0) lb[j] = MU / s;
    }
    __syncthreads();
    {
        const int r = threadIdx.x >> 2, dc = (threadIdx.x & 3) * 16;
        float bj = lb[r];
        const unsigned short* vrow = Vb + ((size_t)h * S_LEN + j0 + r) * HD + dc;
#pragma unroll
        for (int k = 0; k < 16; ++k) t[dc + k][r] = fp8_enc(bf2f(vrow[k]) * bj);
    }
    __syncthreads();
    const int d = threadIdx.x >> 2, jc = (threadIdx.x & 3) * 16;
    unsigned char* out = Vt + ((size_t)h * HD + d) * S_LEN + j0 + jc;
    *(uint4*)out = *(const uint4*)&t[d][jc];
}

// ---------------------------------------------------------------------------
// ctx[i][h*64+d] = a_i*n * sum_j E[h][i][j]*V't[h][d][j].  fp8 MFMA.
// 32 i-rows/block (2 i-tiles/wave, V-frags shared), 4-way j-split,
// 2-stage pipeline with 12 loads in flight.  grid (64, 12), block 256.
__global__ __launch_bounds__(256) void attn_av(
    const unsigned char* __restrict__ E, const float* __restrict__ a,
    const unsigned char* __restrict__ Vt, unsigned short* __restrict__ ctxb) {
    const int h = blockIdx.y;
    const int wave = threadIdx.x >> 6, lane = threadIdx.x & 63;
    const int q = lane >> 4, c = lane & 15;
    const int i0 = blockIdx.x * 32;
    const unsigned char* e0 = E + (size_t)h * S_LEN * S_LEN + (size_t)(i0 + c) * S_LEN;
    const unsigned char* e1 = e0 + (size_t)16 * S_LEN;
    const unsigned char* Vh = Vt + (size_t)h * HD * S_LEN;
    const int jb = wave * 512;
    f32x4 acc[2][4] = {};
    i64_t eN[2][2], vN[4][2];
#pragma unroll
    for (int kk = 0; kk < 2; ++kk) {
        eN[0][kk] = *(const i64_t*)&e0[jb + kk * 32 + q * 8];
        eN[1][kk] = *(const i64_t*)&e1[jb + kk * 32 + q * 8];
#pragma unroll
        for (int s = 0; s < 4; ++s)
            vN[s][kk] = *(const i64_t*)&Vh[(size_t)(s * 16 + c) * S_LEN + jb + kk * 32 + q * 8];
    }
    for (int jt = jb; jt < jb + 512; jt += 64) {
        i64_t eC[2][2], vC[4][2];
#pragma unroll
        for (int kk = 0; kk < 2; ++kk) {
            eC[0][kk] = eN[0][kk]; eC[1][kk] = eN[1][kk];
#pragma unroll
            for (int s = 0; s < 4; ++s) vC[s][kk] = vN[s][kk];
        }
        if (jt + 64 < jb + 512) {
            const int jn = jt + 64;
#pragma unroll
            for (int kk = 0; kk < 2; ++kk) {
                eN[0][kk] = *(const i64_t*)&e0[jn + kk * 32 + q * 8];
                eN[1][kk] = *(const i64_t*)&e1[jn + kk * 32 + q * 8];
#pragma unroll
                for (int s = 0; s < 4; ++s)
                    vN[s][kk] = *(const i64_t*)&Vh[(size_t)(s * 16 + c) * S_LEN + jn + kk * 32 + q * 8];
            }
        }
#pragma unroll
        for (int kk = 0; kk < 2; ++kk)
#pragma unroll
            for (int it = 0; it < 2; ++it)
#pragma unroll
                for (int s = 0; s < 4; ++s)
                    acc[it][s] = __builtin_amdgcn_mfma_f32_16x16x32_fp8_fp8(
                        eC[it][kk], vC[s][kk], acc[it][s], 0, 0, 0);
    }
    __shared__ float lred[3][2][16][64];        // 24 KB
    if (wave != 0) {
#pragma unroll
        for (int it = 0; it < 2; ++it)
#pragma unroll
            for (int s = 0; s < 4; ++s)
#pragma unroll
                for (int r = 0; r < 4; ++r)
                    lred[wave - 1][it][s * 4 + r][lane] = acc[it][s][r];
    }
    __syncthreads();
    if (wave == 0) {
#pragma unroll
        for (int it = 0; it < 2; ++it) {
            float ais[4];
#pragma unroll
            for (int r = 0; r < 4; ++r)
                ais[r] = a[(size_t)h * S_LEN + i0 + it * 16 + q * 4 + r] * 2048.f;
#pragma unroll
            for (int s = 0; s < 4; ++s)
#pragma unroll
                for (int r = 0; r < 4; ++r) {
                    float v = acc[it][s][r] +
                              ((lred[0][it][s * 4 + r][lane] + lred[1][it][s * 4 + r][lane]) +
                               lred[2][it][s * 4 + r][lane]);
                    ctxb[(size_t)(i0 + it * 16 + q * 4 + r) * E_DIM + h * 64 + s * 16 + c] =
                        f2bf(v * ais[r]);
                }
        }
    }
}

// ---------------------------------------------------------------------------
// Y = ctx @ Wo + bo + X (fp32), gll staging, tile 128x64.  grid (12, 16), 256
__global__ __launch_bounds__(256) void out_gemm(
    const unsigned short* __restrict__ ctxb, const unsigned short* __restrict__ Wt,
    const float* __restrict__ bo, const float* __restrict__ X, float* __restrict__ Y) {
    __shared__ unsigned short As[128 * 64];
    __shared__ unsigned short Bs[64 * 64];
    __shared__ float Csf[64 * 64];
    const int n0 = blockIdx.x * 64;
    const int row0 = blockIdx.y * 128;
    const int tid = threadIdx.x;
    const int wave = tid >> 6, lane = tid & 63;
    const int wm = wave & 1, wn = wave >> 1;
    const int q = lane >> 4, c = lane & 15;
    const int lrow = lane >> 3, lk8 = (lane & 7) * 8;
    const unsigned short* Wo3 = Wt + (size_t)3 * E_DIM * E_DIM + (size_t)n0 * E_DIM;
    f32x4 acc[4][2] = {};
    for (int kt = 0; kt < E_DIM; kt += 64) {
        __syncthreads();
#if HAS_GLL
#pragma unroll
        for (int p = 0; p < 4; ++p)
            gll16(&ctxb[(size_t)(row0 + p * 32 + wave * 8 + lrow) * E_DIM + kt + lk8],
                  &As[(p * 32 + wave * 8) * 64]);
#pragma unroll
        for (int p = 0; p < 2; ++p)
            gll16(&Wo3[(size_t)(p * 32 + wave * 8 + lrow) * E_DIM + kt + lk8],
                  &Bs[(p * 32 + wave * 8) * 64]);
#else
        {
            uint4 ta[4], tb[2];
#pragma unroll
            for (int p = 0; p < 4; ++p)
                ta[p] = *(const uint4*)&ctxb[(size_t)(row0 + p * 32 + wave * 8 + lrow) * E_DIM + kt + lk8];
#pragma unroll
            for (int p = 0; p < 2; ++p)
                tb[p] = *(const uint4*)&Wo3[(size_t)(p * 32 + wave * 8 + lrow) * E_DIM + kt + lk8];
#pragma unroll
            for (int p = 0; p < 4; ++p) *(uint4*)&As[(p * 32 + wave * 8 + lrow) * 64 + lk8] = ta[p];
#pragma unroll
            for (int p = 0; p < 2; ++p) *(uint4*)&Bs[(p * 32 + wave * 8 + lrow) * 64 + lk8] = tb[p];
        }
#endif
        __syncthreads();
#pragma unroll
        for (int ks = 0; ks < 2; ++ks) {
            bf16x8 af[4], bfr[2];
#pragma unroll
            for (int mi = 0; mi < 4; ++mi)
                af[mi] = *(const bf16x8*)&As[(wm * 64 + mi * 16 + c) * 64 + ks * 32 + q * 8];
#pragma unroll
            for (int ni = 0; ni < 2; ++ni)
                bfr[ni] = *(const bf16x8*)&Bs[(wn * 32 + ni * 16 + c) * 64 + ks * 32 + q * 8];
#pragma unroll
            for (int mi = 0; mi < 4; ++mi)
#pragma unroll
                for (int ni = 0; ni < 2; ++ni)
                    acc[mi][ni] = __builtin_amdgcn_mfma_f32_16x16x32_bf16(
                        af[mi], bfr[ni], acc[mi][ni], 0, 0, 0);
        }
    }
#pragma unroll
    for (int pp = 0; pp < 2; ++pp) {
        __syncthreads();
        if (wm == pp) {
#pragma unroll
            for (int mi = 0; mi < 4; ++mi)
#pragma unroll
                for (int ni = 0; ni < 2; ++ni)
#pragma unroll
                    for (int r = 0; r < 4; ++r)
                        Csf[(mi * 16 + q * 4 + r) * 64 + wn * 32 + ni * 16 + c] = acc[mi][ni][r];
        }
        __syncthreads();
#pragma unroll
        for (int sp = 0; sp < 4; ++sp) {
            int row = sp * 16 + (tid >> 4);
            int col = (tid & 15) * 4;
            int grow = row0 + pp * 64 + row;
            float4 v = *(const float4*)&Csf[row * 64 + col];
            const float4 xr = *(const float4*)&X[(size_t)grow * E_DIM + n0 + col];
            const float4 bb = *(const float4*)&bo[n0 + col];
            float4 o = {v.x + bb.x + xr.x, v.y + bb.y + xr.y,
                        v.z + bb.z + xr.z, v.w + bb.w + xr.w};
            *(float4*)&Y[(size_t)grow * E_DIM + n0 + col] = o;
        }
    }
}

// ---------------------------------------------------------------------------
// LayerNorm per row.  grid (S), block 256
__global__ __launch_bounds__(256) void layernorm(
    const float* __restrict__ Y, const float* __restrict__ g,
    const float* __restrict__ b, float* __restrict__ out) {
    __shared__ float red[4];
    const int srow = blockIdx.x;
    const float* yr = Y + (size_t)srow * E_DIM;
    const int t = threadIdx.x;
    float xs[3];
    float sum = 0.f;
#pragma unroll
    for (int r = 0; r < 3; ++r) { xs[r] = yr[t + r * 256]; sum += xs[r]; }
#pragma unroll
    for (int off = 32; off; off >>= 1) sum += __shfl_down(sum, off, 64);
    if ((t & 63) == 0) red[t >> 6] = sum;
    __syncthreads();
    sum = red[0] + red[1] + red[2] + red[3];
    const float mu = sum * (1.f / 768.f);
    float vs = 0.f;
#pragma unroll
    for (int r = 0; r < 3; ++r) { float d = xs[r] - mu; vs += d * d; }
    __syncthreads();
#pragma unroll
    for (int off = 32; off; off >>= 1) vs += __shfl_down(vs, off, 64);
    if ((t & 63) == 0) red[t >> 6] = vs;
    __syncthreads();
    vs = red[0] + red[1] + red[2] + red[3];
    const float inv = rsqrtf(vs * (1.f / 768.f) + LN_EPS);
#pragma unroll
    for (int r = 0; r < 3; ++r) {
        int c = t + r * 256;
        out[(size_t)srow * E_DIM + c] = g[c] * (xs[r] - mu) * inv + b[c];
    }
}

// ---------------------------------------------------------------------------
extern "C" void kernel_launch(void* const* d_in, const int* in_sizes, int n_in,
                              void* d_out, int out_size, void* d_ws, size_t ws_size,
                              hipStream_t stream) {
    const float* X    = (const float*)d_in[0];
    const float* Wq   = (const float*)d_in[1];
    const float* bq   = (const float*)d_in[2];
    const float* Wk   = (const float*)d_in[3];
    const float* bk   = (const float*)d_in[4];
    const float* Wv   = (const float*)d_in[5];
    const float* bv   = (const float*)d_in[6];
    const float* Wo   = (const float*)d_in[7];
    const float* bo   = (const float*)d_in[8];
    const float* ln_g = (const float*)d_in[9];
    const float* ln_b = (const float*)d_in[10];
    float* out = (float*)d_out;

    char* p = (char*)d_ws;
    auto alloc = [&](size_t bytes) { char* r = p; p += (bytes + 255) & ~(size_t)255; return r; };
    unsigned short* Xb   = (unsigned short*)alloc((size_t)S_LEN * E_DIM * 2);
    unsigned short* Wt   = (unsigned short*)alloc((size_t)4 * E_DIM * E_DIM * 2);
    unsigned short* Qb   = (unsigned short*)alloc((size_t)NH * S_LEN * HD * 2);
    unsigned short* Kb   = (unsigned short*)alloc((size_t)NH * S_LEN * HD * 2);
    unsigned short* Vb   = (unsigned short*)alloc((size_t)NH * S_LEN * HD * 2);
    unsigned char*  E    = (unsigned char*)alloc((size_t)NH * S_LEN * S_LEN);   // 48 MB fp8
    float*          rp   = (float*)alloc((size_t)NH * 16 * S_LEN * 4);
    float*          av   = (float*)alloc((size_t)NH * S_LEN * 4);
    float*          bv_  = (float*)alloc((size_t)NH * S_LEN * 4);
    float*          tp   = (float*)alloc((size_t)NH * NCH * S_LEN * 4);         // 6 MB
    unsigned char*  Vt   = (unsigned char*)alloc((size_t)NH * HD * S_LEN);
    unsigned short* ctxb = (unsigned short*)alloc((size_t)S_LEN * E_DIM * 2);
    float*          Y    = (float*)alloc((size_t)S_LEN * E_DIM * 4);

    quant_all<<<1536 + 4 * 576, 256, 0, stream>>>(X, Xb, Wq, Wk, Wv, Wo, Wt);
    qkv_gemm<<<dim3(36, 16), 256, 0, stream>>>(Xb, Wt, bq, bk, bv, Qb, Kb, Vb);
    score_exp<<<dim3(16, 32, NH), 256, 0, stream>>>(Qb, Kb, E, rp);

    // Sinkhorn: 3 fused streaming passes (CH=32)
    sink_pass<<<dim3(NCH, NH), 256, 0, stream>>>(E, bv_, rp, nullptr, tp, 1);    // a1->tp
    col_combine<<<NH * S_LEN / 256, 256, 0, stream>>>(tp, bv_);                  // b1
    sink_pass<<<dim3(NCH, NH), 256, 0, stream>>>(E, bv_, rp, nullptr, tp, 0);    // a2->tp
    col_combine<<<NH * S_LEN / 256, 256, 0, stream>>>(tp, bv_);                  // b2
    sink_pass<<<dim3(NCH, NH), 256, 0, stream>>>(E, bv_, rp, av, tp, 0);         // a3->tp (+a3 out)
    col_combine_scale<<<dim3(S_LEN / 64, NH), 256, 0, stream>>>(tp, Vb, Vt);     // b3 + scale V

    attn_av<<<dim3(S_LEN / 32, NH), 256, 0, stream>>>(E, av, Vt, ctxb);
    out_gemm<<<dim3(12, 16), 256, 0, stream>>>(ctxb, Wt, bo, X, Y);
    layernorm<<<S_LEN, 256, 0, stream>>>(Y, ln_g, ln_b, out);
}

// Round 15
// 226.057 us; speedup vs baseline: 4.6336x; 1.0162x over previous
//
#include <hip/hip_runtime.h>
#include <math.h>

#define S_LEN 2048
#define E_DIM 768
#define NH    12
#define HD    64
#define MU    (1.0f/2048.0f)
#define LN_EPS 1e-12f
#define CH    32            // sink_pass chunk rows
#define NCH   (S_LEN/CH)    // 64 chunks

typedef __attribute__((ext_vector_type(8))) short bf16x8;   // 8 bf16 (4 VGPRs)
typedef __attribute__((ext_vector_type(4))) float f32x4;    // MFMA accumulator
typedef __attribute__((ext_vector_type(2))) float f32x2;
typedef long i64_t;                                          // 8 fp8 (2 VGPRs)

__device__ __forceinline__ unsigned short f2bf(float f) {   // RNE fp32->bf16
    unsigned u = __float_as_uint(f);
    u += 0x7fff + ((u >> 16) & 1);
    return (unsigned short)(u >> 16);
}
__device__ __forceinline__ float bf2f(unsigned short h) {
    return __uint_as_float(((unsigned)h) << 16);
}

// ---- fp8 e4m3 (OCP) helpers ----
__device__ __forceinline__ unsigned char fp8_enc(float f) {
#if __has_builtin(__builtin_amdgcn_cvt_pk_fp8_f32)
    return (unsigned char)(__builtin_amdgcn_cvt_pk_fp8_f32(f, f, 0, false) & 0xFF);
#else
    float m = fminf(fabsf(f), 448.f) * 0x1p-120f;
    unsigned b = __float_as_uint(m);
    unsigned s = (__float_as_uint(f) >> 24) & 0x80u;
    b += 0x7FFFFu + ((b >> 20) & 1u);
    return (unsigned char)(s | ((b >> 20) & 0x7Fu));
#endif
}
// pack 4 floats -> 4 fp8 bytes in one dword
__device__ __forceinline__ unsigned fp8_pack4(float e0, float e1, float e2, float e3) {
#if __has_builtin(__builtin_amdgcn_cvt_pk_fp8_f32)
    unsigned u = __builtin_amdgcn_cvt_pk_fp8_f32(e0, e1, 0, false);
    u = __builtin_amdgcn_cvt_pk_fp8_f32(e2, e3, u, true);
    return u;
#else
    return (unsigned)fp8_enc(e0) | ((unsigned)fp8_enc(e1) << 8) |
           ((unsigned)fp8_enc(e2) << 16) | ((unsigned)fp8_enc(e3) << 24);
#endif
}
__device__ __forceinline__ float fp8_dec1(unsigned char u) {
    unsigned bits = ((u & 0x80u) << 24) | ((u & 0x7Fu) << 20);
    return __uint_as_float(bits) * 0x1p+120f;
}
__device__ __forceinline__ f32x2 fp8_dec_lo(unsigned v) {
#if __has_builtin(__builtin_amdgcn_cvt_pk_f32_fp8)
    return __builtin_amdgcn_cvt_pk_f32_fp8(v, false);
#else
    f32x2 r; r.x = fp8_dec1(v & 0xFF); r.y = fp8_dec1((v >> 8) & 0xFF); return r;
#endif
}
__device__ __forceinline__ f32x2 fp8_dec_hi(unsigned v) {
#if __has_builtin(__builtin_amdgcn_cvt_pk_f32_fp8)
    return __builtin_amdgcn_cvt_pk_f32_fp8(v, true);
#else
    f32x2 r; r.x = fp8_dec1((v >> 16) & 0xFF); r.y = fp8_dec1(v >> 24); return r;
#endif
}

// ---- async global->LDS, 16 B per lane (dest = wave-uniform base + lane*16) ----
#if defined(__has_builtin)
#if __has_builtin(__builtin_amdgcn_global_load_lds)
#define HAS_GLL 1
#endif
#endif
#if HAS_GLL
__device__ __forceinline__ void gll16(const void* g, void* l) {
    __builtin_amdgcn_global_load_lds(
        (__attribute__((address_space(1))) void*)(void*)g,
        (__attribute__((address_space(3))) void*)l, 16, 0, 0);
}
#endif

// ---------------------------------------------------------------------------
// Merged preprocessing: X fp32->bf16 (blocks 0..1535) + 4x W fp32->bf16^T
// (blocks 1536..3839: 4 matrices x 576 32x32-tiles).  block 256.
__global__ __launch_bounds__(256) void quant_all(
    const float* __restrict__ X, unsigned short* __restrict__ Xb,
    const float* __restrict__ W0, const float* __restrict__ W1,
    const float* __restrict__ W2, const float* __restrict__ W3,
    unsigned short* __restrict__ Wt) {
    const int b = blockIdx.x;
    if (b < 1536) {                 // X quant: one float4 per thread
        int i = b * 256 + threadIdx.x;
        const float4 v = ((const float4*)X)[i];
        ushort4 o = { f2bf(v.x), f2bf(v.y), f2bf(v.z), f2bf(v.w) };
        ((ushort4*)Xb)[i] = o;
        return;
    }
    const int wb = b - 1536;
    const int z = wb / 576, t = wb % 576;
    const float* W = (z == 0) ? W0 : (z == 1) ? W1 : (z == 2) ? W2 : W3;
    __shared__ unsigned short tsm[32][33];
    const int n0 = (t % 24) * 32, k0 = (t / 24) * 32;
    const int c = threadIdx.x & 31, r8 = threadIdx.x >> 5;
#pragma unroll
    for (int rr = 0; rr < 32; rr += 8) {
        int k = k0 + r8 + rr;
        tsm[c][r8 + rr] = f2bf(W[(size_t)k * E_DIM + n0 + c]);
    }
    __syncthreads();
    unsigned short* out = Wt + (size_t)z * E_DIM * E_DIM;
#pragma unroll
    for (int rr = 0; rr < 32; rr += 8) {
        int n = n0 + r8 + rr;
        out[(size_t)n * E_DIM + k0 + c] = tsm[r8 + rr][c];
    }
}

// ---------------------------------------------------------------------------
// Fused QKV GEMM, global_load_lds staging, tile 128x64, BK=64.
// grid (36 n-tiles, 16 row-tiles), block 256.  All outputs bf16 [h][s][64].
__global__ __launch_bounds__(256) void qkv_gemm(
    const unsigned short* __restrict__ Xb, const unsigned short* __restrict__ Wt,
    const float* __restrict__ bq, const float* __restrict__ bk, const float* __restrict__ bv,
    unsigned short* __restrict__ Qb, unsigned short* __restrict__ Kb,
    unsigned short* __restrict__ Vb) {
    __shared__ unsigned short As[128 * 64];     // unpadded: required by gll
    __shared__ unsigned short Bs[64 * 64];
    const int n0 = blockIdx.x * 64;
    const int row0 = blockIdx.y * 128;
    const int tid = threadIdx.x;
    const int wave = tid >> 6, lane = tid & 63;
    const int wm = wave & 1, wn = wave >> 1;
    const int q = lane >> 4, c = lane & 15;
    const int lrow = lane >> 3, lk8 = (lane & 7) * 8;
    const unsigned short* Wb = Wt + (size_t)n0 * E_DIM;
    f32x4 acc[4][2] = {};
    for (int kt = 0; kt < E_DIM; kt += 64) {
        __syncthreads();
#if HAS_GLL
#pragma unroll
        for (int p = 0; p < 4; ++p)
            gll16(&Xb[(size_t)(row0 + p * 32 + wave * 8 + lrow) * E_DIM + kt + lk8],
                  &As[(p * 32 + wave * 8) * 64]);
#pragma unroll
        for (int p = 0; p < 2; ++p)
            gll16(&Wb[(size_t)(p * 32 + wave * 8 + lrow) * E_DIM + kt + lk8],
                  &Bs[(p * 32 + wave * 8) * 64]);
#else
        {
            uint4 ta[4], tb[2];
#pragma unroll
            for (int p = 0; p < 4; ++p)
                ta[p] = *(const uint4*)&Xb[(size_t)(row0 + p * 32 + wave * 8 + lrow) * E_DIM + kt + lk8];
#pragma unroll
            for (int p = 0; p < 2; ++p)
                tb[p] = *(const uint4*)&Wb[(size_t)(p * 32 + wave * 8 + lrow) * E_DIM + kt + lk8];
#pragma unroll
            for (int p = 0; p < 4; ++p) *(uint4*)&As[(p * 32 + wave * 8 + lrow) * 64 + lk8] = ta[p];
#pragma unroll
            for (int p = 0; p < 2; ++p) *(uint4*)&Bs[(p * 32 + wave * 8 + lrow) * 64 + lk8] = tb[p];
        }
#endif
        __syncthreads();
#pragma unroll
        for (int ks = 0; ks < 2; ++ks) {
            bf16x8 af[4], bfr[2];
#pragma unroll
            for (int mi = 0; mi < 4; ++mi)
                af[mi] = *(const bf16x8*)&As[(wm * 64 + mi * 16 + c) * 64 + ks * 32 + q * 8];
#pragma unroll
            for (int ni = 0; ni < 2; ++ni)
                bfr[ni] = *(const bf16x8*)&Bs[(wn * 32 + ni * 16 + c) * 64 + ks * 32 + q * 8];
#pragma unroll
            for (int mi = 0; mi < 4; ++mi)
#pragma unroll
                for (int ni = 0; ni < 2; ++ni)
                    acc[mi][ni] = __builtin_amdgcn_mfma_f32_16x16x32_bf16(
                        af[mi], bfr[ni], acc[mi][ni], 0, 0, 0);
        }
    }
    const int z = n0 / E_DIM;
    const int h = (n0 % E_DIM) >> 6;
    const float* bias = (z == 0) ? bq : (z == 1) ? bk : bv;
    unsigned short* outp = (z == 0) ? Qb : (z == 1) ? Kb : Vb;
    __syncthreads();
    unsigned short* Cs = As;                    // reuse 16 KB for repack
#pragma unroll
    for (int ni = 0; ni < 2; ++ni) {
        const int col = wn * 32 + ni * 16 + c;
        const float bb = bias[h * 64 + col];
#pragma unroll
        for (int mi = 0; mi < 4; ++mi)
#pragma unroll
            for (int r = 0; r < 4; ++r)
                Cs[(wm * 64 + mi * 16 + q * 4 + r) * 64 + col] = f2bf(acc[mi][ni][r] + bb);
    }
    __syncthreads();
#pragma unroll
    for (int pp = 0; pp < 4; ++pp) {
        int row = pp * 32 + (tid >> 3);
        *(uint4*)&outp[((size_t)h * S_LEN + row0 + row) * HD + (tid & 7) * 8] =
            *(const uint4*)&Cs[row * 64 + (tid & 7) * 8];
    }
}

// ---------------------------------------------------------------------------
// E = exp(QK^T/8) -> fp8.  SWAPPED operands (A=K, B=Q): D[m=j][n=i].
// grid (16 j-tiles(128), 32 i-tiles(64), 12 h), block 256.
__global__ __launch_bounds__(256) void score_exp(
    const unsigned short* __restrict__ Qb, const unsigned short* __restrict__ Kb,
    unsigned char* __restrict__ E, float* __restrict__ rp) {
    const int h = blockIdx.z;
    const int i0 = blockIdx.y * 64, j0 = blockIdx.x * 128;
    const int tid = threadIdx.x;
    const int wave = tid >> 6, lane = tid & 63;
    const int q = lane >> 4, c = lane & 15;
    __shared__ unsigned short Qs[64 * 64];
    __shared__ unsigned short Ks[128 * 64];
    __shared__ unsigned char  Es[64 * 144];     // row stride 144 B (pad: 2-way max)
    __shared__ float red[4][64];
    const unsigned short* Qh = Qb + (size_t)h * S_LEN * HD;
    const unsigned short* Kh = Kb + (size_t)h * S_LEN * HD;
    const int lrow = lane >> 3, lk8 = (lane & 7) * 8;
#if HAS_GLL
#pragma unroll
    for (int p = 0; p < 2; ++p)
        gll16(&Qh[(size_t)(i0 + p * 32 + wave * 8 + lrow) * HD + lk8],
              &Qs[(p * 32 + wave * 8) * 64]);
#pragma unroll
    for (int p = 0; p < 4; ++p)
        gll16(&Kh[(size_t)(j0 + p * 32 + wave * 8 + lrow) * HD + lk8],
              &Ks[(p * 32 + wave * 8) * 64]);
#else
    {
        uint4 tq[2], tk[4];
#pragma unroll
        for (int p = 0; p < 2; ++p)
            tq[p] = *(const uint4*)&Qh[(size_t)(i0 + p * 32 + wave * 8 + lrow) * HD + lk8];
#pragma unroll
        for (int p = 0; p < 4; ++p)
            tk[p] = *(const uint4*)&Kh[(size_t)(j0 + p * 32 + wave * 8 + lrow) * HD + lk8];
#pragma unroll
        for (int p = 0; p < 2; ++p) *(uint4*)&Qs[(p * 32 + wave * 8 + lrow) * 64 + lk8] = tq[p];
#pragma unroll
        for (int p = 0; p < 4; ++p) *(uint4*)&Ks[(p * 32 + wave * 8 + lrow) * 64 + lk8] = tk[p];
    }
#endif
    __syncthreads();
    f32x4 acc[2][4] = {};                       // [jt][it]; wave covers j = wave*32 + jt*16
#pragma unroll
    for (int dt = 0; dt < HD; dt += 32) {
        bf16x8 af[2], bq_[4];
#pragma unroll
        for (int jt = 0; jt < 2; ++jt)
            af[jt] = *(const bf16x8*)&Ks[(wave * 32 + jt * 16 + c) * 64 + dt + q * 8];
#pragma unroll
        for (int it = 0; it < 4; ++it)
            bq_[it] = *(const bf16x8*)&Qs[(it * 16 + c) * 64 + dt + q * 8];
#pragma unroll
        for (int jt = 0; jt < 2; ++jt)
#pragma unroll
            for (int it = 0; it < 4; ++it)
                acc[jt][it] = __builtin_amdgcn_mfma_f32_16x16x32_bf16(
                    af[jt], bq_[it], acc[jt][it], 0, 0, 0);
    }
    float rsum[4] = {0.f, 0.f, 0.f, 0.f};
#pragma unroll
    for (int jt = 0; jt < 2; ++jt)
#pragma unroll
        for (int it = 0; it < 4; ++it) {
            float e0 = __expf(acc[jt][it][0] * 0.125f);
            float e1 = __expf(acc[jt][it][1] * 0.125f);
            float e2 = __expf(acc[jt][it][2] * 0.125f);
            float e3 = __expf(acc[jt][it][3] * 0.125f);
            rsum[it] += (e0 + e1) + (e2 + e3);
            *(unsigned*)&Es[(it * 16 + c) * 144 + wave * 32 + jt * 16 + q * 4] =
                fp8_pack4(e0, e1, e2, e3);
        }
#pragma unroll
    for (int it = 0; it < 4; ++it) {
        rsum[it] += __shfl_xor(rsum[it], 16, 64);
        rsum[it] += __shfl_xor(rsum[it], 32, 64);
    }
    if (q == 0) {
#pragma unroll
        for (int it = 0; it < 4; ++it) red[wave][it * 16 + c] = rsum[it];
    }
    __syncthreads();
    {   // coalesced full-line E stores: 4 threads cover one 128-B row
        const int row = tid >> 2, off = (tid & 3) * 32;
        uint4 v0 = *(const uint4*)&Es[row * 144 + off];
        uint4 v1 = *(const uint4*)&Es[row * 144 + off + 16];
        unsigned char* dst = E + ((size_t)h * S_LEN + i0 + row) * S_LEN + j0 + off;
        *(uint4*)dst = v0;
        *(uint4*)(dst + 16) = v1;
    }
    if (tid < 64)
        rp[((size_t)h * 16 + blockIdx.x) * S_LEN + i0 + tid] =
            (red[0][tid] + red[1][tid]) + (red[2][tid] + red[3][tid]);
}

// ---------------------------------------------------------------------------
// Fused Sinkhorn pass, streaming, CH=32 rows/chunk, bf16 tp:
//   phase 1: a[i] = mu / (E·b)[i]  (rows direct global->VGPR, b in padded LDS)
//   phase 2: tp[h][chunk][j] = bf16( sum_i a[i]*E[i][j] )  (re-read, 16-deep)
// grid (NCH=64, 12), block 256 (4 waves, 8 rows/wave).  LDS ~9 KB.
#define BPAD(j) ((j) + ((j) >> 4))              // +1 float pad per 16 -> conflict-free
__global__ __launch_bounds__(256) void sink_pass(
    const unsigned char* __restrict__ E, const float* __restrict__ bvec,
    const float* __restrict__ rp, float* __restrict__ aout,
    unsigned short* __restrict__ tpart, int use_rp) {
    __shared__ float lb[2048 + 128];            // padded b
    __shared__ float la[CH];
    const int h = blockIdx.y, chunk = blockIdx.x;
    const int tid = threadIdx.x, wave = tid >> 6, lane = tid & 63;
    const unsigned char* gbase = E + ((size_t)h * S_LEN + chunk * CH) * S_LEN;
    if (use_rp) {
        if (tid < CH) {
            float s = 0.f;
#pragma unroll
            for (int jt = 0; jt < 16; ++jt)
                s += rp[((size_t)h * 16 + jt) * S_LEN + chunk * CH + tid];
            la[tid] = MU / s;
        }
        __syncthreads();
    } else {
        {   // stage b (padded layout)
            const float* bg = bvec + (size_t)h * S_LEN;
#pragma unroll
            for (int p = 0; p < 8; ++p) {
                int j = p * 256 + tid;
                lb[BPAD(j)] = bg[j];
            }
        }
        __syncthreads();
        // phase 1: wave w -> rows w*8..w*8+7; lane covers j = lane*16 (+1024)
        const int jA = lane * 16, jB = 1024 + lane * 16;
        float bA[16], bB[16];
#pragma unroll
        for (int m = 0; m < 16; ++m) { bA[m] = lb[BPAD(jA + m)]; bB[m] = lb[BPAD(jB + m)]; }
#pragma unroll
        for (int rg = 0; rg < 2; ++rg) {        // 2 groups of 4 rows
            uint4 eA[4], eB[4];
#pragma unroll
            for (int rr = 0; rr < 4; ++rr) {
                const unsigned char* er = gbase + (size_t)(wave * 8 + rg * 4 + rr) * S_LEN;
                eA[rr] = *(const uint4*)&er[jA];
                eB[rr] = *(const uint4*)&er[jB];
            }
#pragma unroll
            for (int rr = 0; rr < 4; ++rr) {
                float s = 0.f;
                unsigned wA[4] = {eA[rr].x, eA[rr].y, eA[rr].z, eA[rr].w};
                unsigned wB[4] = {eB[rr].x, eB[rr].y, eB[rr].z, eB[rr].w};
#pragma unroll
                for (int m = 0; m < 4; ++m) {
                    f32x2 lo = fp8_dec_lo(wA[m]), hi = fp8_dec_hi(wA[m]);
                    s += lo.x * bA[m*4] + lo.y * bA[m*4+1] + hi.x * bA[m*4+2] + hi.y * bA[m*4+3];
                    lo = fp8_dec_lo(wB[m]); hi = fp8_dec_hi(wB[m]);
                    s += lo.x * bB[m*4] + lo.y * bB[m*4+1] + hi.x * bB[m*4+2] + hi.y * bB[m*4+3];
                }
#pragma unroll
                for (int off = 32; off; off >>= 1) s += __shfl_xor(s, off, 64);
                if (lane == 0) la[wave * 8 + rg * 4 + rr] = MU / s;
            }
        }
        __syncthreads();
    }
    if (aout != nullptr && tid < CH)
        aout[(size_t)h * S_LEN + chunk * CH + tid] = la[tid];
    // phase 2: column partials; re-read rows from global (L2-hot), 16-deep
    {
        const int j0 = tid * 8;
        const unsigned char* eb = gbase + j0;
        float acc[8] = {};
#pragma unroll
        for (int g = 0; g < 2; ++g) {
            uint2 e[16];
#pragma unroll
            for (int r = 0; r < 16; ++r)
                e[r] = *(const uint2*)&eb[(size_t)(g * 16 + r) * S_LEN];
#pragma unroll
            for (int r = 0; r < 16; ++r) {
                float ar = la[g * 16 + r];
                f32x2 lo = fp8_dec_lo(e[r].x), hi = fp8_dec_hi(e[r].x);
                acc[0] += lo.x * ar; acc[1] += lo.y * ar; acc[2] += hi.x * ar; acc[3] += hi.y * ar;
                lo = fp8_dec_lo(e[r].y); hi = fp8_dec_hi(e[r].y);
                acc[4] += lo.x * ar; acc[5] += lo.y * ar; acc[6] += hi.x * ar; acc[7] += hi.y * ar;
            }
        }
        bf16x8 o;
#pragma unroll
        for (int k = 0; k < 8; ++k) o[k] = (short)f2bf(acc[k]);
        *(bf16x8*)&tpart[((size_t)h * NCH + chunk) * S_LEN + j0] = o;
    }
}

// b[h][j] = mu / sum_chunk tp (bf16).  grid (NH*S/256), block 256
__global__ __launch_bounds__(256) void col_combine(
    const unsigned short* __restrict__ tpart, float* __restrict__ bout) {
    int g = blockIdx.x * 256 + threadIdx.x;
    int h = g >> 11, j = g & 2047;
    float s = 0.f;
#pragma unroll 8
    for (int c = 0; c < NCH; ++c) s += bf2f(tpart[((size_t)h * NCH + c) * S_LEN + j]);
    bout[g] = MU / s;
}

// ---------------------------------------------------------------------------
// Fused b3-combine + V scaling: b[j]=mu/sum tp, V't[h][d][j]=fp8(b[j]*V[j][d])
// grid (S/64 = 32, 12), block 256
__global__ __launch_bounds__(256) void col_combine_scale(
    const unsigned short* __restrict__ tpart, const unsigned short* __restrict__ Vb,
    unsigned char* __restrict__ Vt) {
    const int h = blockIdx.y, j0 = blockIdx.x * 64;
    __shared__ float lb[64];
    __shared__ unsigned char t[64][80];
    {
        int j = threadIdx.x >> 2, seg = threadIdx.x & 3;
        float s = 0.f;
#pragma unroll
        for (int cc = 0; cc < NCH / 4; ++cc)
            s += bf2f(tpart[((size_t)h * NCH + seg * (NCH / 4) + cc) * S_LEN + j0 + j]);
        s += __shfl_down(s, 2, 4);
        s += __shfl_down(s, 1, 4);
        if (seg == 0) lb[j] = MU / s;
    }
    __syncthreads();
    {
        const int r = threadIdx.x >> 2, dc = (threadIdx.x & 3) * 16;
        float bj = lb[r];
        const unsigned short* vrow = Vb + ((size_t)h * S_LEN + j0 + r) * HD + dc;
#pragma unroll
        for (int k = 0; k < 16; ++k) t[dc + k][r] = fp8_enc(bf2f(vrow[k]) * bj);
    }
    __syncthreads();
    const int d = threadIdx.x >> 2, jc = (threadIdx.x & 3) * 16;
    unsigned char* out = Vt + ((size_t)h * HD + d) * S_LEN + j0 + jc;
    *(uint4*)out = *(const uint4*)&t[d][jc];
}

// ---------------------------------------------------------------------------
// ctx[i][h*64+d] = a_i*n * sum_j E[h][i][j]*V't[h][d][j].  fp8 MFMA.
// 32 i-rows/block (2 i-tiles/wave, V-frags shared), 4-way j-split,
// 2-stage pipeline with 12 loads in flight.  grid (64, 12), block 256.
__global__ __launch_bounds__(256) void attn_av(
    const unsigned char* __restrict__ E, const float* __restrict__ a,
    const unsigned char* __restrict__ Vt, unsigned short* __restrict__ ctxb) {
    const int h = blockIdx.y;
    const int wave = threadIdx.x >> 6, lane = threadIdx.x & 63;
    const int q = lane >> 4, c = lane & 15;
    const int i0 = blockIdx.x * 32;
    const unsigned char* e0 = E + (size_t)h * S_LEN * S_LEN + (size_t)(i0 + c) * S_LEN;
    const unsigned char* e1 = e0 + (size_t)16 * S_LEN;
    const unsigned char* Vh = Vt + (size_t)h * HD * S_LEN;
    const int jb = wave * 512;
    f32x4 acc[2][4] = {};
    i64_t eN[2][2], vN[4][2];
#pragma unroll
    for (int kk = 0; kk < 2; ++kk) {
        eN[0][kk] = *(const i64_t*)&e0[jb + kk * 32 + q * 8];
        eN[1][kk] = *(const i64_t*)&e1[jb + kk * 32 + q * 8];
#pragma unroll
        for (int s = 0; s < 4; ++s)
            vN[s][kk] = *(const i64_t*)&Vh[(size_t)(s * 16 + c) * S_LEN + jb + kk * 32 + q * 8];
    }
    for (int jt = jb; jt < jb + 512; jt += 64) {
        i64_t eC[2][2], vC[4][2];
#pragma unroll
        for (int kk = 0; kk < 2; ++kk) {
            eC[0][kk] = eN[0][kk]; eC[1][kk] = eN[1][kk];
#pragma unroll
            for (int s = 0; s < 4; ++s) vC[s][kk] = vN[s][kk];
        }
        if (jt + 64 < jb + 512) {
            const int jn = jt + 64;
#pragma unroll
            for (int kk = 0; kk < 2; ++kk) {
                eN[0][kk] = *(const i64_t*)&e0[jn + kk * 32 + q * 8];
                eN[1][kk] = *(const i64_t*)&e1[jn + kk * 32 + q * 8];
#pragma unroll
                for (int s = 0; s < 4; ++s)
                    vN[s][kk] = *(const i64_t*)&Vh[(size_t)(s * 16 + c) * S_LEN + jn + kk * 32 + q * 8];
            }
        }
#pragma unroll
        for (int kk = 0; kk < 2; ++kk)
#pragma unroll
            for (int it = 0; it < 2; ++it)
#pragma unroll
                for (int s = 0; s < 4; ++s)
                    acc[it][s] = __builtin_amdgcn_mfma_f32_16x16x32_fp8_fp8(
                        eC[it][kk], vC[s][kk], acc[it][s], 0, 0, 0);
    }
    __shared__ float lred[3][2][16][64];        // 24 KB
    if (wave != 0) {
#pragma unroll
        for (int it = 0; it < 2; ++it)
#pragma unroll
            for (int s = 0; s < 4; ++s)
#pragma unroll
                for (int r = 0; r < 4; ++r)
                    lred[wave - 1][it][s * 4 + r][lane] = acc[it][s][r];
    }
    __syncthreads();
    if (wave == 0) {
#pragma unroll
        for (int it = 0; it < 2; ++it) {
            float ais[4];
#pragma unroll
            for (int r = 0; r < 4; ++r)
                ais[r] = a[(size_t)h * S_LEN + i0 + it * 16 + q * 4 + r] * 2048.f;
#pragma unroll
            for (int s = 0; s < 4; ++s)
#pragma unroll
                for (int r = 0; r < 4; ++r) {
                    float v = acc[it][s][r] +
                              ((lred[0][it][s * 4 + r][lane] + lred[1][it][s * 4 + r][lane]) +
                               lred[2][it][s * 4 + r][lane]);
                    ctxb[(size_t)(i0 + it * 16 + q * 4 + r) * E_DIM + h * 64 + s * 16 + c] =
                        f2bf(v * ais[r]);
                }
        }
    }
}

// ---------------------------------------------------------------------------
// Y = ctx @ Wo + bo + X (fp32), gll staging, tile 128x64.  grid (12, 16), 256
__global__ __launch_bounds__(256) void out_gemm(
    const unsigned short* __restrict__ ctxb, const unsigned short* __restrict__ Wt,
    const float* __restrict__ bo, const float* __restrict__ X, float* __restrict__ Y) {
    __shared__ unsigned short As[128 * 64];
    __shared__ unsigned short Bs[64 * 64];
    __shared__ float Csf[64 * 64];
    const int n0 = blockIdx.x * 64;
    const int row0 = blockIdx.y * 128;
    const int tid = threadIdx.x;
    const int wave = tid >> 6, lane = tid & 63;
    const int wm = wave & 1, wn = wave >> 1;
    const int q = lane >> 4, c = lane & 15;
    const int lrow = lane >> 3, lk8 = (lane & 7) * 8;
    const unsigned short* Wo3 = Wt + (size_t)3 * E_DIM * E_DIM + (size_t)n0 * E_DIM;
    f32x4 acc[4][2] = {};
    for (int kt = 0; kt < E_DIM; kt += 64) {
        __syncthreads();
#if HAS_GLL
#pragma unroll
        for (int p = 0; p < 4; ++p)
            gll16(&ctxb[(size_t)(row0 + p * 32 + wave * 8 + lrow) * E_DIM + kt + lk8],
                  &As[(p * 32 + wave * 8) * 64]);
#pragma unroll
        for (int p = 0; p < 2; ++p)
            gll16(&Wo3[(size_t)(p * 32 + wave * 8 + lrow) * E_DIM + kt + lk8],
                  &Bs[(p * 32 + wave * 8) * 64]);
#else
        {
            uint4 ta[4], tb[2];
#pragma unroll
            for (int p = 0; p < 4; ++p)
                ta[p] = *(const uint4*)&ctxb[(size_t)(row0 + p * 32 + wave * 8 + lrow) * E_DIM + kt + lk8];
#pragma unroll
            for (int p = 0; p < 2; ++p)
                tb[p] = *(const uint4*)&Wo3[(size_t)(p * 32 + wave * 8 + lrow) * E_DIM + kt + lk8];
#pragma unroll
            for (int p = 0; p < 4; ++p) *(uint4*)&As[(p * 32 + wave * 8 + lrow) * 64 + lk8] = ta[p];
#pragma unroll
            for (int p = 0; p < 2; ++p) *(uint4*)&Bs[(p * 32 + wave * 8 + lrow) * 64 + lk8] = tb[p];
        }
#endif
        __syncthreads();
#pragma unroll
        for (int ks = 0; ks < 2; ++ks) {
            bf16x8 af[4], bfr[2];
#pragma unroll
            for (int mi = 0; mi < 4; ++mi)
                af[mi] = *(const bf16x8*)&As[(wm * 64 + mi * 16 + c) * 64 + ks * 32 + q * 8];
#pragma unroll
            for (int ni = 0; ni < 2; ++ni)
                bfr[ni] = *(const bf16x8*)&Bs[(wn * 32 + ni * 16 + c) * 64 + ks * 32 + q * 8];
#pragma unroll
            for (int mi = 0; mi < 4; ++mi)
#pragma unroll
                for (int ni = 0; ni < 2; ++ni)
                    acc[mi][ni] = __builtin_amdgcn_mfma_f32_16x16x32_bf16(
                        af[mi], bfr[ni], acc[mi][ni], 0, 0, 0);
        }
    }
#pragma unroll
    for (int pp = 0; pp < 2; ++pp) {
        __syncthreads();
        if (wm == pp) {
#pragma unroll
            for (int mi = 0; mi < 4; ++mi)
#pragma unroll
                for (int ni = 0; ni < 2; ++ni)
#pragma unroll
                    for (int r = 0; r < 4; ++r)
                        Csf[(mi * 16 + q * 4 + r) * 64 + wn * 32 + ni * 16 + c] = acc[mi][ni][r];
        }
        __syncthreads();
#pragma unroll
        for (int sp = 0; sp < 4; ++sp) {
            int row = sp * 16 + (tid >> 4);
            int col = (tid & 15) * 4;
            int grow = row0 + pp * 64 + row;
            float4 v = *(const float4*)&Csf[row * 64 + col];
            const float4 xr = *(const float4*)&X[(size_t)grow * E_DIM + n0 + col];
            const float4 bb = *(const float4*)&bo[n0 + col];
            float4 o = {v.x + bb.x + xr.x, v.y + bb.y + xr.y,
                        v.z + bb.z + xr.z, v.w + bb.w + xr.w};
            *(float4*)&Y[(size_t)grow * E_DIM + n0 + col] = o;
        }
    }
}

// ---------------------------------------------------------------------------
// LayerNorm per row.  grid (S), block 256
__global__ __launch_bounds__(256) void layernorm(
    const float* __restrict__ Y, const float* __restrict__ g,
    const float* __restrict__ b, float* __restrict__ out) {
    __shared__ float red[4];
    const int srow = blockIdx.x;
    const float* yr = Y + (size_t)srow * E_DIM;
    const int t = threadIdx.x;
    float xs[3];
    float sum = 0.f;
#pragma unroll
    for (int r = 0; r < 3; ++r) { xs[r] = yr[t + r * 256]; sum += xs[r]; }
#pragma unroll
    for (int off = 32; off; off >>= 1) sum += __shfl_down(sum, off, 64);
    if ((t & 63) == 0) red[t >> 6] = sum;
    __syncthreads();
    sum = red[0] + red[1] + red[2] + red[3];
    const float mu = sum * (1.f / 768.f);
    float vs = 0.f;
#pragma unroll
    for (int r = 0; r < 3; ++r) { float d = xs[r] - mu; vs += d * d; }
    __syncthreads();
#pragma unroll
    for (int off = 32; off; off >>= 1) vs += __shfl_down(vs, off, 64);
    if ((t & 63) == 0) red[t >> 6] = vs;
    __syncthreads();
    vs = red[0] + red[1] + red[2] + red[3];
    const float inv = rsqrtf(vs * (1.f / 768.f) + LN_EPS);
#pragma unroll
    for (int r = 0; r < 3; ++r) {
        int c = t + r * 256;
        out[(size_t)srow * E_DIM + c] = g[c] * (xs[r] - mu) * inv + b[c];
    }
}

// ---------------------------------------------------------------------------
extern "C" void kernel_launch(void* const* d_in, const int* in_sizes, int n_in,
                              void* d_out, int out_size, void* d_ws, size_t ws_size,
                              hipStream_t stream) {
    const float* X    = (const float*)d_in[0];
    const float* Wq   = (const float*)d_in[1];
    const float* bq   = (const float*)d_in[2];
    const float* Wk   = (const float*)d_in[3];
    const float* bk   = (const float*)d_in[4];
    const float* Wv   = (const float*)d_in[5];
    const float* bv   = (const float*)d_in[6];
    const float* Wo   = (const float*)d_in[7];
    const float* bo   = (const float*)d_in[8];
    const float* ln_g = (const float*)d_in[9];
    const float* ln_b = (const float*)d_in[10];
    float* out = (float*)d_out;

    char* p = (char*)d_ws;
    auto alloc = [&](size_t bytes) { char* r = p; p += (bytes + 255) & ~(size_t)255; return r; };
    unsigned short* Xb   = (unsigned short*)alloc((size_t)S_LEN * E_DIM * 2);
    unsigned short* Wt   = (unsigned short*)alloc((size_t)4 * E_DIM * E_DIM * 2);
    unsigned short* Qb   = (unsigned short*)alloc((size_t)NH * S_LEN * HD * 2);
    unsigned short* Kb   = (unsigned short*)alloc((size_t)NH * S_LEN * HD * 2);
    unsigned short* Vb   = (unsigned short*)alloc((size_t)NH * S_LEN * HD * 2);
    unsigned char*  E    = (unsigned char*)alloc((size_t)NH * S_LEN * S_LEN);   // 48 MB fp8
    float*          rp   = (float*)alloc((size_t)NH * 16 * S_LEN * 4);
    float*          av   = (float*)alloc((size_t)NH * S_LEN * 4);
    float*          bv_  = (float*)alloc((size_t)NH * S_LEN * 4);
    unsigned short* tp   = (unsigned short*)alloc((size_t)NH * NCH * S_LEN * 2); // 3 MB bf16
    unsigned char*  Vt   = (unsigned char*)alloc((size_t)NH * HD * S_LEN);
    unsigned short* ctxb = (unsigned short*)alloc((size_t)S_LEN * E_DIM * 2);
    float*          Y    = (float*)alloc((size_t)S_LEN * E_DIM * 4);

    quant_all<<<1536 + 4 * 576, 256, 0, stream>>>(X, Xb, Wq, Wk, Wv, Wo, Wt);
    qkv_gemm<<<dim3(36, 16), 256, 0, stream>>>(Xb, Wt, bq, bk, bv, Qb, Kb, Vb);
    score_exp<<<dim3(16, 32, NH), 256, 0, stream>>>(Qb, Kb, E, rp);

    // Sinkhorn: 3 fused streaming passes (CH=32, bf16 tp)
    sink_pass<<<dim3(NCH, NH), 256, 0, stream>>>(E, bv_, rp, nullptr, tp, 1);    // a1->tp
    col_combine<<<NH * S_LEN / 256, 256, 0, stream>>>(tp, bv_);                  // b1
    sink_pass<<<dim3(NCH, NH), 256, 0, stream>>>(E, bv_, rp, nullptr, tp, 0);    // a2->tp
    col_combine<<<NH * S_LEN / 256, 256, 0, stream>>>(tp, bv_);                  // b2
    sink_pass<<<dim3(NCH, NH), 256, 0, stream>>>(E, bv_, rp, av, tp, 0);         // a3->tp (+a3 out)
    col_combine_scale<<<dim3(S_LEN / 64, NH), 256, 0, stream>>>(tp, Vb, Vt);     // b3 + scale V

    attn_av<<<dim3(S_LEN / 32, NH), 256, 0, stream>>>(E, av, Vt, ctxb);
    out_gemm<<<dim3(12, 16), 256, 0, stream>>>(ctxb, Wt, bo, X, Y);
    layernorm<<<S_LEN, 256, 0, stream>>>(Y, ln_g, ln_b, out);
}